// Round 1
// baseline (2463.152 us; speedup 1.0000x reference)
//
#include <hip/hip_runtime.h>
#include <cstdint>

// ---------------- problem constants ----------------
constexpr int Dm       = 1024;
constexpr int Hh       = 16;
constexpr int HD       = 64;
constexpr int TPF      = 256;
constexpr int CHUNKS   = 4;
constexpr int TXT      = 226;
constexpr int SEQ_TXT  = 904;        // CHUNKS*TXT
constexpr int VID_LEN  = 3328;       // FRAMES*TPF
constexpr int CHUNK_VID= 1024;       // (PREFIX+ATTN)*TPF
constexpr int Tt       = 1250;       // TXT + CHUNK_VID
constexpr int M_QKV    = 5000;       // CHUNKS*Tt
constexpr int SEQm     = 4232;       // SEQ_TXT + VID_LEN
constexpr int STRIDE_V = 768;        // ATTN*TPF
constexpr float EPSc   = 1e-6f;
constexpr float SCALEc = 0.125f;     // 1/sqrt(64)
constexpr float THETAc = 10000.f;

constexpr int SEGL = 128;
constexpr int NSEG = (SEQm + SEGL - 1) / SEGL;   // 34

// reversal mapping (involution): text chunks flipped, video flipped
__device__ __forceinline__ int rev_map(int i) {
    if (i < SEQ_TXT) {
        int c = i / TXT, o = i - c * TXT;
        return (CHUNKS - 1 - c) * TXT + o;
    }
    int j = i - SEQ_TXT;
    return SEQ_TXT + (VID_LEN - 1 - j);
}

// ---------------- kernel 1: assemble cur [5000 x 1024] ----------------
__global__ __launch_bounds__(256) void build_cur(
    const float* __restrict__ vid, const float* __restrict__ txt,
    float* __restrict__ cur) {
    int idx = blockIdx.x * 256 + threadIdx.x;           // one float4 each
    int row = idx >> 8, c4 = (idx & 255) * 4;
    int c = row / Tt, t = row - c * Tt;
    float4 x;
    if (t < TXT)
        x = *(const float4*)(txt + (size_t)(c * TXT + t) * Dm + c4);
    else
        x = *(const float4*)(vid + (size_t)(c * STRIDE_V + (t - TXT)) * Dm + c4);
    *(float4*)(cur + (size_t)row * Dm + c4) = x;
}

// ---------------- kernel 2: fp32 tiled GEMM  C[M,1024] = A[M,1024] @ W + bias --
__global__ __launch_bounds__(256) void gemm_fp32(
    const float* __restrict__ A, const float* __restrict__ Bw,
    const float* __restrict__ bias, float* __restrict__ C, int M) {
    __shared__ float As[16][72];
    __shared__ float Bs[16][72];
    const int tid = threadIdx.x;
    const int rowBase = blockIdx.y * 64, colBase = blockIdx.x * 64;
    const int tx = tid & 15, ty = tid >> 4;
    const int am = tid >> 2, ak = (tid & 3) * 4;   // A stage: row am, k-off ak
    const int bk = tid >> 4, bn = (tid & 15) * 4;  // B stage
    float acc[4][4] = {};
    for (int kk = 0; kk < 1024; kk += 16) {
        float4 a4 = make_float4(0.f, 0.f, 0.f, 0.f);
        int arow = rowBase + am;
        if (arow < M) a4 = *(const float4*)(A + (size_t)arow * 1024 + kk + ak);
        float4 b4 = *(const float4*)(Bw + (size_t)(kk + bk) * 1024 + colBase + bn);
        __syncthreads();
        As[ak + 0][am] = a4.x; As[ak + 1][am] = a4.y;
        As[ak + 2][am] = a4.z; As[ak + 3][am] = a4.w;
        *(float4*)&Bs[bk][bn] = b4;
        __syncthreads();
#pragma unroll
        for (int k2 = 0; k2 < 16; ++k2) {
            float4 av = *(float4*)&As[k2][ty * 4];
            float4 bv = *(float4*)&Bs[k2][tx * 4];
            float ar[4] = {av.x, av.y, av.z, av.w};
            float br[4] = {bv.x, bv.y, bv.z, bv.w};
#pragma unroll
            for (int i = 0; i < 4; ++i)
#pragma unroll
                for (int j = 0; j < 4; ++j)
                    acc[i][j] = fmaf(ar[i], br[j], acc[i][j]);
        }
    }
    float bb[4] = {0.f, 0.f, 0.f, 0.f};
    if (bias) {
        float4 b4 = *(const float4*)(bias + colBase + tx * 4);
        bb[0] = b4.x; bb[1] = b4.y; bb[2] = b4.z; bb[3] = b4.w;
    }
#pragma unroll
    for (int i = 0; i < 4; ++i) {
        int row = rowBase + ty * 4 + i;
        if (row < M) {
            float4 o = make_float4(acc[i][0] + bb[0], acc[i][1] + bb[1],
                                   acc[i][2] + bb[2], acc[i][3] + bb[3]);
            *(float4*)(C + (size_t)row * 1024 + colBase + tx * 4) = o;
        }
    }
}

// ---------------- kernel 3: per-head LayerNorm + RoPE3D, relayout --------------
// in : qpre/kpre/vpre [5000][1024] (row = c*Tt+t, col = h*64+d)
// out: q/k/v [64][Tt][64]  (q pre-scaled by SCALE)
__global__ __launch_bounds__(256) void lnrope(
    const float* __restrict__ qpre, const float* __restrict__ kpre,
    const float* __restrict__ vpre,
    const float* __restrict__ qn_w, const float* __restrict__ qn_b,
    const float* __restrict__ kn_w, const float* __restrict__ kn_b,
    float* __restrict__ q, float* __restrict__ k, float* __restrict__ v) {
    int wid  = blockIdx.x * 4 + (threadIdx.x >> 6);
    int lane = threadIdx.x & 63;
    if (wid >= M_QKV * Hh) return;
    int h = wid & 15, row = wid >> 4;
    int c = row / Tt, t = row - c * Tt;
    size_t src = (size_t)row * Dm + h * HD + lane;
    float qv = qpre[src], kv = kpre[src], vv = vpre[src];

    auto wsum = [](float x) {
#pragma unroll
        for (int o = 32; o; o >>= 1) x += __shfl_xor(x, o);
        return x;
    };
    float qmu = wsum(qv) * (1.f / 64.f);
    float qd  = qv - qmu;
    float qvar = wsum(qd * qd) * (1.f / 64.f);
    float qn = qd * rsqrtf(qvar + EPSc) * qn_w[lane] + qn_b[lane];

    float kmu = wsum(kv) * (1.f / 64.f);
    float kd  = kv - kmu;
    float kvar = wsum(kd * kd) * (1.f / 64.f);
    float kn = kd * rsqrtf(kvar + EPSc) * kn_w[lane] + kn_b[lane];

    if (t >= TXT) {
        int pos = t - TXT;
        int f = pos >> 8, rem = pos & 255, hp = rem >> 4, wp = rem & 15;
        int dim, p, dl;
        if (lane < 16)      { dim = 16; p = f;  dl = lane; }
        else if (lane < 40) { dim = 24; p = hp; dl = lane - 16; }
        else                { dim = 24; p = wp; dl = lane - 40; }
        int half = dim >> 1;
        int i = (dl < half) ? dl : dl - half;
        float ang = (float)p * powf(THETAc, -2.0f * (float)i / (float)dim);
        float cs = cosf(ang), sn = sinf(ang);
        int partner = (dl < half) ? (lane + half) : (lane - half);
        float qo = __shfl(qn, partner);
        float ko = __shfl(kn, partner);
        qn = (dl < half) ? (qn * cs - qo * sn) : (qo * sn + qn * cs);
        kn = (dl < half) ? (kn * cs - ko * sn) : (ko * sn + kn * cs);
    }
    size_t dst = ((size_t)(c * Hh + h) * Tt + t) * HD + lane;
    q[dst] = qn * SCALEc;
    k[dst] = kn;
    v[dst] = vv;
}

// ---------------- kernel 4: flash attention, 16 q rows / block -----------------
__global__ __launch_bounds__(256) void attn_kernel(
    const float* __restrict__ q, const float* __restrict__ k,
    const float* __restrict__ v, float* __restrict__ out) {
    const int ch = blockIdx.y;           // c*H + h
    const int c = ch >> 4, h = ch & 15;
    const int qbase = blockIdx.x * 16;
    const int tid = threadIdx.x, wave = tid >> 6, lane = tid & 63;

    __shared__ float4 Kt4[16][64];   // Kt4[d4][j] = K[j][4d4..4d4+3]
    __shared__ float  Vt[64][64];    // Vt[j][d]
    __shared__ float4 Qs4[16][16];   // Qs4[localRow][d4]
    __shared__ float4 Ps4[4][64];    // [wave][j] -> p for r=0..3

    const float* qb = q + (size_t)ch * Tt * HD;
    const float* kb = k + (size_t)ch * Tt * HD;
    const float* vb = v + (size_t)ch * Tt * HD;

    {   // stage Q tile
        int row = tid >> 4, d4 = tid & 15;
        int t = qbase + row;
        float4 qv = make_float4(0.f, 0.f, 0.f, 0.f);
        if (t < Tt) qv = *(const float4*)(qb + (size_t)t * HD + d4 * 4);
        Qs4[row][d4] = qv;
    }

    float m_r[4], l_r[4], acc_r[4];
#pragma unroll
    for (int r = 0; r < 4; ++r) { m_r[r] = -1e30f; l_r[r] = 0.f; acc_r[r] = 0.f; }

    for (int kb0 = 0; kb0 < Tt; kb0 += 64) {
        int lim = min(64, Tt - kb0);
        __syncthreads();
#pragma unroll
        for (int it = 0; it < 4; ++it) {     // stage K(transposed), V
            int lin = tid + it * 256;
            int j = lin >> 4, d4 = lin & 15;
            int t = kb0 + j;
            float4 kvv = make_float4(0.f, 0.f, 0.f, 0.f);
            float4 vvv = make_float4(0.f, 0.f, 0.f, 0.f);
            if (t < Tt) {
                kvv = *(const float4*)(kb + (size_t)t * HD + d4 * 4);
                vvv = *(const float4*)(vb + (size_t)t * HD + d4 * 4);
            }
            Kt4[d4][j] = kvv;
            *(float4*)&Vt[j][d4 * 4] = vvv;
        }
        __syncthreads();

        // scores: lane plays "j"
        float s[4] = {0.f, 0.f, 0.f, 0.f};
#pragma unroll
        for (int d4 = 0; d4 < 16; ++d4) {
            float4 kvv = Kt4[d4][lane];
#pragma unroll
            for (int r = 0; r < 4; ++r) {
                float4 qv = Qs4[wave * 4 + r][d4];
                s[r] += qv.x * kvv.x + qv.y * kvv.y + qv.z * kvv.z + qv.w * kvv.w;
            }
        }
        bool vj = (lane < lim);
        float pv[4];
#pragma unroll
        for (int r = 0; r < 4; ++r) {
            float sv = vj ? s[r] : -1e30f;
            float mx = sv;
#pragma unroll
            for (int o = 32; o; o >>= 1) mx = fmaxf(mx, __shfl_xor(mx, o));
            float m_new = fmaxf(m_r[r], mx);
            float alpha = expf(m_r[r] - m_new);
            float p = expf(sv - m_new);
            float ps = p;
#pragma unroll
            for (int o = 32; o; o >>= 1) ps += __shfl_xor(ps, o);
            l_r[r] = l_r[r] * alpha + ps;
            acc_r[r] *= alpha;
            m_r[r] = m_new;
            pv[r] = p;
        }
        Ps4[wave][lane] = make_float4(pv[0], pv[1], pv[2], pv[3]);

        // PV: lane plays "d"
#pragma unroll 8
        for (int j = 0; j < 64; ++j) {
            float4 pj = Ps4[wave][j];
            float vvv = Vt[j][lane];
            acc_r[0] = fmaf(pj.x, vvv, acc_r[0]);
            acc_r[1] = fmaf(pj.y, vvv, acc_r[1]);
            acc_r[2] = fmaf(pj.z, vvv, acc_r[2]);
            acc_r[3] = fmaf(pj.w, vvv, acc_r[3]);
        }
    }
#pragma unroll
    for (int r = 0; r < 4; ++r) {
        int t = qbase + wave * 4 + r;
        if (t < Tt)
            out[(size_t)(c * Tt + t) * Dm + h * HD + lane] = acc_r[r] / l_r[r];
    }
}

// ---------------- kernel 5: scatter/average back to sequence -------------------
__global__ __launch_bounds__(256) void scatter_emb(
    const float* __restrict__ proj, float* __restrict__ emb) {
    int idx = blockIdx.x * 256 + threadIdx.x;
    int row = idx >> 8, c4 = (idx & 255) * 4;
    float4 o;
    if (row < SEQ_TXT) {
        int c = row / TXT, t = row - c * TXT;
        o = *(const float4*)(proj + (size_t)(c * Tt + t) * Dm + c4);
    } else {
        int p = row - SEQ_TXT;
        float sx = 0.f, sy = 0.f, sz = 0.f, sw = 0.f; int cnt = 0;
#pragma unroll
        for (int c = 0; c < CHUNKS; ++c) {
            int off = p - c * STRIDE_V;
            if (off >= 0 && off < CHUNK_VID) {
                float4 x = *(const float4*)(proj + (size_t)(c * Tt + TXT + off) * Dm + c4);
                sx += x.x; sy += x.y; sz += x.z; sw += x.w; ++cnt;
            }
        }
        float inv = 1.f / (float)cnt;
        o = make_float4(sx * inv, sy * inv, sz * inv, sw * inv);
    }
    *(float4*)(emb + (size_t)row * Dm + c4) = o;
}

// ---------------- SSM scan (3-pass segmented) ----------------------------------
__global__ __launch_bounds__(256) void scan_carry(
    const float* __restrict__ u, const float* __restrict__ gate,
    float* __restrict__ carry, int perm) {
    int ch = blockIdx.x * 256 + threadIdx.x;
    int seg = blockIdx.y;
    float g = 1.f / (1.f + expf(-gate[ch]));
    int t0 = seg * SEGL, t1 = min(SEQm, t0 + SEGL);
    float hv = 0.f;
    for (int t = t0; t < t1; ++t) {
        int rt = perm ? rev_map(t) : t;
        hv = fmaf(g, hv, u[(size_t)rt * Dm + ch]);
    }
    carry[(size_t)seg * Dm + ch] = hv;
}

__global__ __launch_bounds__(256) void scan_combine(
    const float* __restrict__ carry, const float* __restrict__ gate,
    float* __restrict__ inc) {
    int ch = blockIdx.x * 256 + threadIdx.x;
    float g = 1.f / (1.f + expf(-gate[ch]));
    float gl = powf(g, (float)SEGL);
    float S = 0.f;
    for (int s = 0; s < NSEG; ++s) {
        inc[(size_t)s * Dm + ch] = S;
        int len = min(SEGL, SEQm - s * SEGL);
        float A = (len == SEGL) ? gl : powf(g, (float)len);
        S = fmaf(A, S, carry[(size_t)s * Dm + ch]);
    }
}

__global__ __launch_bounds__(256) void scan_final(
    const float* __restrict__ u, const float* __restrict__ gate,
    const float* __restrict__ inc, float* __restrict__ hbuf, int perm) {
    int ch = blockIdx.x * 256 + threadIdx.x;
    int seg = blockIdx.y;
    float g = 1.f / (1.f + expf(-gate[ch]));
    int t0 = seg * SEGL, t1 = min(SEQm, t0 + SEGL);
    float hv = inc[(size_t)seg * Dm + ch];
    for (int t = t0; t < t1; ++t) {
        int rt = perm ? rev_map(t) : t;
        hv = fmaf(g, hv, u[(size_t)rt * Dm + ch]);
        hbuf[(size_t)rt * Dm + ch] = hv;
    }
}

// ---------------- elementwise combines -----------------------------------------
__global__ __launch_bounds__(256) void combine1(
    const float* __restrict__ emb, const float* __restrict__ y,
    const float* __restrict__ fg_t, const float* __restrict__ fg_v,
    float* __restrict__ emb2) {
    int idx = blockIdx.x * 256 + threadIdx.x;
    int row = idx >> 8, c4 = (idx & 255) * 4;
    const float* fg = (row < SEQ_TXT) ? fg_t : fg_v;
    float4 e = *(const float4*)(emb + (size_t)row * Dm + c4);
    float4 yy = *(const float4*)(y + (size_t)row * Dm + c4);
    float4 o = make_float4(e.x + tanhf(fg[c4 + 0]) * yy.x,
                           e.y + tanhf(fg[c4 + 1]) * yy.y,
                           e.z + tanhf(fg[c4 + 2]) * yy.z,
                           e.w + tanhf(fg[c4 + 3]) * yy.w);
    *(float4*)(emb2 + (size_t)row * Dm + c4) = o;
}

__global__ __launch_bounds__(256) void final_combine(
    const float* __restrict__ emb2, const float* __restrict__ y2,
    const float* __restrict__ bg_t, const float* __restrict__ bg_v,
    float* __restrict__ outp) {
    int idx = blockIdx.x * 256 + threadIdx.x;
    int row = idx >> 8, c4 = (idx & 255) * 4;
    const float* bg = (row < SEQ_TXT) ? bg_t : bg_v;
    int drow = (row >= SEQ_TXT) ? (row - SEQ_TXT) : (VID_LEN + row);
    float4 e = *(const float4*)(emb2 + (size_t)row * Dm + c4);
    float4 yy = *(const float4*)(y2 + (size_t)row * Dm + c4);
    float4 o = make_float4(e.x + tanhf(bg[c4 + 0]) * yy.x,
                           e.y + tanhf(bg[c4 + 1]) * yy.y,
                           e.z + tanhf(bg[c4 + 2]) * yy.z,
                           e.w + tanhf(bg[c4 + 3]) * yy.w);
    *(float4*)(outp + (size_t)drow * Dm + c4) = o;
}

// ---------------- host-side orchestration --------------------------------------
extern "C" void kernel_launch(void* const* d_in, const int* in_sizes, int n_in,
                              void* d_out, int out_size, void* d_ws, size_t ws_size,
                              hipStream_t stream) {
    const float* vid_emb = (const float*)d_in[0];
    const float* text_emb= (const float*)d_in[1];
    const float* Wq = (const float*)d_in[2];  const float* bq = (const float*)d_in[3];
    const float* Wk = (const float*)d_in[4];  const float* bk = (const float*)d_in[5];
    const float* Wv = (const float*)d_in[6];  const float* bv = (const float*)d_in[7];
    const float* Wo = (const float*)d_in[8];  const float* bo = (const float*)d_in[9];
    const float* qn_w = (const float*)d_in[10]; const float* qn_b = (const float*)d_in[11];
    const float* kn_w = (const float*)d_in[12]; const float* kn_b = (const float*)d_in[13];
    const float* Win  = (const float*)d_in[14]; const float* Wout = (const float*)d_in[15];
    const float* gate = (const float*)d_in[16];
    const float* fg_t = (const float*)d_in[17]; const float* fg_v = (const float*)d_in[18];
    const float* bg_t = (const float*)d_in[19]; const float* bg_v = (const float*)d_in[20];

    // workspace layout (floats)
    const size_t R1 = 0;                       // 5,120,000 : cur -> attn_out -> emb
    const size_t R2 = 5120000;                 // 15,360,000: q/k/v_pre -> u,h,y
    const size_t R3 = 20480000;                // 15,360,000: q/k/v -> proj -> emb2
    const size_t R4 = 35840000;                // carries
    const size_t need = (size_t)(35840000 + 2 * NSEG * Dm) * sizeof(float);
    if (ws_size < need) return;                // ws too small: bail (will show as mismatch)

    float* ws   = (float*)d_ws;
    float* cur  = ws + R1;
    float* qpre = ws + R2;
    float* kpre = ws + R2 + 5120000;
    float* vpre = ws + R2 + 10240000;
    float* qT   = ws + R3;
    float* kT   = ws + R3 + 5120000;
    float* vT   = ws + R3 + 10240000;
    float* attn_out = ws + R1;                 // over dead cur
    float* proj = ws + R3;                     // over dead qT
    float* emb  = ws + R1;                     // over dead attn_out
    float* u    = ws + R2;                     // over dead qpre
    float* hbuf = ws + R2 + 4333568;
    float* ybuf = ws + R2 + 8667136;
    float* emb2 = ws + R3;                     // over dead proj
    float* carry= ws + R4;
    float* incb = ws + R4 + (size_t)NSEG * Dm;
    float* outp = (float*)d_out;

    build_cur<<<M_QKV, 256, 0, stream>>>(vid_emb, text_emb, cur);

    dim3 gq(16, (M_QKV + 63) / 64);
    gemm_fp32<<<gq, 256, 0, stream>>>(cur, Wq, bq, qpre, M_QKV);
    gemm_fp32<<<gq, 256, 0, stream>>>(cur, Wk, bk, kpre, M_QKV);
    gemm_fp32<<<gq, 256, 0, stream>>>(cur, Wv, bv, vpre, M_QKV);

    lnrope<<<(M_QKV * Hh) / 4, 256, 0, stream>>>(qpre, kpre, vpre, qn_w, qn_b,
                                                 kn_w, kn_b, qT, kT, vT);

    dim3 ga((Tt + 15) / 16, CHUNKS * Hh);
    attn_kernel<<<ga, 256, 0, stream>>>(qT, kT, vT, attn_out);

    gemm_fp32<<<gq, 256, 0, stream>>>(attn_out, Wo, bo, proj, M_QKV);

    scatter_emb<<<SEQm, 256, 0, stream>>>(proj, emb);

    dim3 gu(16, (SEQm + 63) / 64);
    dim3 gscan(Dm / 256, NSEG);

    // SSM forward
    gemm_fp32<<<gu, 256, 0, stream>>>(emb, Win, nullptr, u, SEQm);
    scan_carry<<<gscan, 256, 0, stream>>>(u, gate, carry, 0);
    scan_combine<<<Dm / 256, 256, 0, stream>>>(carry, gate, incb);
    scan_final<<<gscan, 256, 0, stream>>>(u, gate, incb, hbuf, 0);
    gemm_fp32<<<gu, 256, 0, stream>>>(hbuf, Wout, nullptr, ybuf, SEQm);
    combine1<<<SEQm, 256, 0, stream>>>(emb, ybuf, fg_t, fg_v, emb2);

    // SSM backward (permuted scan; GEMMs commute with row permutation)
    gemm_fp32<<<gu, 256, 0, stream>>>(emb2, Win, nullptr, u, SEQm);
    scan_carry<<<gscan, 256, 0, stream>>>(u, gate, carry, 1);
    scan_combine<<<Dm / 256, 256, 0, stream>>>(carry, gate, incb);
    scan_final<<<gscan, 256, 0, stream>>>(u, gate, incb, hbuf, 1);
    gemm_fp32<<<gu, 256, 0, stream>>>(hbuf, Wout, nullptr, ybuf, SEQm);

    final_combine<<<SEQm, 256, 0, stream>>>(emb2, ybuf, bg_t, bg_v, outp);
}

// Round 2
// 1684.910 us; speedup vs baseline: 1.4619x; 1.4619x over previous
//
#include <hip/hip_runtime.h>
#include <cstdint>

// ---------------- problem constants ----------------
constexpr int Dm       = 1024;
constexpr int Hh       = 16;
constexpr int HD       = 64;
constexpr int TPF      = 256;
constexpr int CHUNKS   = 4;
constexpr int TXT      = 226;
constexpr int SEQ_TXT  = 904;        // CHUNKS*TXT
constexpr int VID_LEN  = 3328;       // FRAMES*TPF
constexpr int CHUNK_VID= 1024;       // (PREFIX+ATTN)*TPF
constexpr int Tt       = 1250;       // TXT + CHUNK_VID
constexpr int M_QKV    = 5000;       // CHUNKS*Tt
constexpr int SEQm     = 4232;       // SEQ_TXT + VID_LEN
constexpr int STRIDE_V = 768;        // ATTN*TPF
constexpr float EPSc   = 1e-6f;
constexpr float SCALEc = 0.125f;     // 1/sqrt(64)
constexpr float THETAc = 10000.f;

constexpr int SEGL = 128;
constexpr int NSEG = (SEQm + SEGL - 1) / SEGL;   // 34

typedef __attribute__((ext_vector_type(8))) short bf16x8;
typedef __attribute__((ext_vector_type(4))) float f32x4;

__device__ __forceinline__ ushort f2bf(float x) {
    uint32_t u = __float_as_uint(x);
    u += 0x7FFFu + ((u >> 16) & 1u);
    return (ushort)(u >> 16);
}
__device__ __forceinline__ float bf2f(ushort b) {
    return __uint_as_float(((uint32_t)b) << 16);
}

// reversal mapping (involution): text chunks flipped, video flipped
__device__ __forceinline__ int rev_map(int i) {
    if (i < SEQ_TXT) {
        int c = i / TXT, o = i - c * TXT;
        return (CHUNKS - 1 - c) * TXT + o;
    }
    int j = i - SEQ_TXT;
    return SEQ_TXT + (VID_LEN - 1 - j);
}

// ---------------- kernel 1: assemble cur [5000 x 1024] ----------------
__global__ __launch_bounds__(256) void build_cur(
    const float* __restrict__ vid, const float* __restrict__ txt,
    float* __restrict__ cur) {
    int idx = blockIdx.x * 256 + threadIdx.x;           // one float4 each
    int row = idx >> 8, c4 = (idx & 255) * 4;
    int c = row / Tt, t = row - c * Tt;
    float4 x;
    if (t < TXT)
        x = *(const float4*)(txt + (size_t)(c * TXT + t) * Dm + c4);
    else
        x = *(const float4*)(vid + (size_t)(c * STRIDE_V + (t - TXT)) * Dm + c4);
    *(float4*)(cur + (size_t)row * Dm + c4) = x;
}

// ---------------- kernel 2: fp32 tiled GEMM  C[M,1024] = A[M,1024] @ W + bias --
__global__ __launch_bounds__(256) void gemm_fp32(
    const float* __restrict__ A, const float* __restrict__ Bw,
    const float* __restrict__ bias, float* __restrict__ C, int M) {
    __shared__ float As[16][72];
    __shared__ float Bs[16][72];
    const int tid = threadIdx.x;
    const int rowBase = blockIdx.y * 64, colBase = blockIdx.x * 64;
    const int tx = tid & 15, ty = tid >> 4;
    const int am = tid >> 2, ak = (tid & 3) * 4;   // A stage: row am, k-off ak
    const int bk = tid >> 4, bn = (tid & 15) * 4;  // B stage
    float acc[4][4] = {};
    for (int kk = 0; kk < 1024; kk += 16) {
        float4 a4 = make_float4(0.f, 0.f, 0.f, 0.f);
        int arow = rowBase + am;
        if (arow < M) a4 = *(const float4*)(A + (size_t)arow * 1024 + kk + ak);
        float4 b4 = *(const float4*)(Bw + (size_t)(kk + bk) * 1024 + colBase + bn);
        __syncthreads();
        As[ak + 0][am] = a4.x; As[ak + 1][am] = a4.y;
        As[ak + 2][am] = a4.z; As[ak + 3][am] = a4.w;
        *(float4*)&Bs[bk][bn] = b4;
        __syncthreads();
#pragma unroll
        for (int k2 = 0; k2 < 16; ++k2) {
            float4 av = *(float4*)&As[k2][ty * 4];
            float4 bv = *(float4*)&Bs[k2][tx * 4];
            float ar[4] = {av.x, av.y, av.z, av.w};
            float br[4] = {bv.x, bv.y, bv.z, bv.w};
#pragma unroll
            for (int i = 0; i < 4; ++i)
#pragma unroll
                for (int j = 0; j < 4; ++j)
                    acc[i][j] = fmaf(ar[i], br[j], acc[i][j]);
        }
    }
    float bb[4] = {0.f, 0.f, 0.f, 0.f};
    if (bias) {
        float4 b4 = *(const float4*)(bias + colBase + tx * 4);
        bb[0] = b4.x; bb[1] = b4.y; bb[2] = b4.z; bb[3] = b4.w;
    }
#pragma unroll
    for (int i = 0; i < 4; ++i) {
        int row = rowBase + ty * 4 + i;
        if (row < M) {
            float4 o = make_float4(acc[i][0] + bb[0], acc[i][1] + bb[1],
                                   acc[i][2] + bb[2], acc[i][3] + bb[3]);
            *(float4*)(C + (size_t)row * 1024 + colBase + tx * 4) = o;
        }
    }
}

// ---------------- kernel 3: per-head LayerNorm + RoPE3D, split-bf16 relayout ---
// in : qpre/kpre/vpre [5000][1024] (row = c*Tt+t, col = h*64+d)
// out: ushort planes [64ch][Tt][64]: qhi,qlo (pre-scaled by SCALE), khi,klo, vb
__global__ __launch_bounds__(256) void lnrope(
    const float* __restrict__ qpre, const float* __restrict__ kpre,
    const float* __restrict__ vpre,
    const float* __restrict__ qn_w, const float* __restrict__ qn_b,
    const float* __restrict__ kn_w, const float* __restrict__ kn_b,
    ushort* __restrict__ qhi, ushort* __restrict__ qlo,
    ushort* __restrict__ khi, ushort* __restrict__ klo,
    ushort* __restrict__ vb) {
    int wid  = blockIdx.x * 4 + (threadIdx.x >> 6);
    int lane = threadIdx.x & 63;
    if (wid >= M_QKV * Hh) return;
    int h = wid & 15, row = wid >> 4;
    int c = row / Tt, t = row - c * Tt;
    size_t src = (size_t)row * Dm + h * HD + lane;
    float qv = qpre[src], kv = kpre[src], vv = vpre[src];

    auto wsum = [](float x) {
#pragma unroll
        for (int o = 32; o; o >>= 1) x += __shfl_xor(x, o);
        return x;
    };
    float qmu = wsum(qv) * (1.f / 64.f);
    float qd  = qv - qmu;
    float qvar = wsum(qd * qd) * (1.f / 64.f);
    float qn = qd * rsqrtf(qvar + EPSc) * qn_w[lane] + qn_b[lane];

    float kmu = wsum(kv) * (1.f / 64.f);
    float kd  = kv - kmu;
    float kvar = wsum(kd * kd) * (1.f / 64.f);
    float kn = kd * rsqrtf(kvar + EPSc) * kn_w[lane] + kn_b[lane];

    if (t >= TXT) {
        int pos = t - TXT;
        int f = pos >> 8, rem = pos & 255, hp = rem >> 4, wp = rem & 15;
        int dim, p, dl;
        if (lane < 16)      { dim = 16; p = f;  dl = lane; }
        else if (lane < 40) { dim = 24; p = hp; dl = lane - 16; }
        else                { dim = 24; p = wp; dl = lane - 40; }
        int half = dim >> 1;
        int i = (dl < half) ? dl : dl - half;
        float ang = (float)p * powf(THETAc, -2.0f * (float)i / (float)dim);
        float cs = cosf(ang), sn = sinf(ang);
        int partner = (dl < half) ? (lane + half) : (lane - half);
        float qo = __shfl(qn, partner);
        float ko = __shfl(kn, partner);
        qn = (dl < half) ? (qn * cs - qo * sn) : (qo * sn + qn * cs);
        kn = (dl < half) ? (kn * cs - ko * sn) : (ko * sn + kn * cs);
    }
    size_t dst = ((size_t)(c * Hh + h) * Tt + t) * HD + lane;
    float qs = qn * SCALEc;
    ushort qh = f2bf(qs);
    qhi[dst] = qh;
    qlo[dst] = f2bf(qs - bf2f(qh));
    ushort kh = f2bf(kn);
    khi[dst] = kh;
    klo[dst] = f2bf(kn - bf2f(kh));
    vb[dst]  = f2bf(vv);
}

// ---------------- kernel 4: MFMA flash attention, 64 q rows / block ------------
// grid (ceil(Tt/64), 64ch); 4 waves, each wave owns 16 q rows; 32-key steps.
__global__ __launch_bounds__(256) void attn_mfma(
    const ushort* __restrict__ qhi, const ushort* __restrict__ qlo,
    const ushort* __restrict__ khi, const ushort* __restrict__ klo,
    const ushort* __restrict__ vb, float* __restrict__ out) {
    const int ch = blockIdx.y;                 // c*16 + h
    const int c = ch >> 4, h = ch & 15;
    const int qbase = blockIdx.x * 64;
    const int tid = threadIdx.x, w = tid >> 6, lane = tid & 63;
    const int lrow = lane & 15, quad = lane >> 4;

    __shared__ ushort KH[32][88];     // k_hi tile, [key][dim]
    __shared__ ushort KL[32][88];     // k_lo tile
    __shared__ ushort VT[64][40];     // v tile transposed, [dim][key]
    __shared__ ushort PB[4][16][40];  // per-wave P, [qrow][key]

    const size_t chb = (size_t)ch * Tt * HD;

    // Q fragments (A-layout: lane holds Q[lrow][quad*8+j]), two 32-dim halves
    bf16x8 qh0 = {0,0,0,0,0,0,0,0}, qh1 = qh0, ql0 = qh0, ql1 = qh0;
    {
        int qr = qbase + w * 16 + lrow;
        if (qr < Tt) {
            const ushort* p = qhi + chb + (size_t)qr * HD + quad * 8;
            qh0 = *(const bf16x8*)p;
            qh1 = *(const bf16x8*)(p + 32);
            const ushort* p2 = qlo + chb + (size_t)qr * HD + quad * 8;
            ql0 = *(const bf16x8*)p2;
            ql1 = *(const bf16x8*)(p2 + 32);
        }
    }

    f32x4 accO[4];                    // O C-frags over 4 d-tiles
#pragma unroll
    for (int dt = 0; dt < 4; ++dt) accO[dt] = (f32x4){0.f, 0.f, 0.f, 0.f};
    float m_i[4], l_i[4];
#pragma unroll
    for (int r = 0; r < 4; ++r) { m_i[r] = -1e30f; l_i[r] = 0.f; }

    const int kr = tid >> 3, kc8 = (tid & 7) * 8;   // K staging coords

    for (int kb = 0; kb < Tt; kb += 32) {
        __syncthreads();
        // ---- stage K hi/lo [32][64] ----
        {
            bf16x8 z = {0,0,0,0,0,0,0,0};
            bf16x8 a = z, b = z;
            if (kb + kr < Tt) {
                a = *(const bf16x8*)(khi + chb + (size_t)(kb + kr) * HD + kc8);
                b = *(const bf16x8*)(klo + chb + (size_t)(kb + kr) * HD + kc8);
            }
            *(bf16x8*)&KH[kr][kc8] = a;
            *(bf16x8*)&KL[kr][kc8] = b;
            // ---- stage V transposed: thread (w,lane) loads 8 keys at dim=lane
            short vv[8];
#pragma unroll
            for (int i = 0; i < 8; ++i) {
                int key = kb + w * 8 + i;
                vv[i] = (key < Tt) ? (short)vb[chb + (size_t)key * HD + lane] : (short)0;
            }
            *(bf16x8*)&VT[lane][w * 8] = *(bf16x8*)vv;
        }
        __syncthreads();

        // ---- QK^T: two 16-key tiles, split-bf16 (3 products) ----
        f32x4 s0 = {0.f, 0.f, 0.f, 0.f}, s1 = s0;
#pragma unroll
        for (int t = 0; t < 2; ++t) {
            const ushort* kh = &KH[t * 16 + lrow][quad * 8];
            const ushort* kl = &KL[t * 16 + lrow][quad * 8];
            bf16x8 kh0 = *(const bf16x8*)kh;
            bf16x8 kh1 = *(const bf16x8*)(kh + 32);
            bf16x8 kl0 = *(const bf16x8*)kl;
            bf16x8 kl1 = *(const bf16x8*)(kl + 32);
            f32x4 acc = (t == 0) ? s0 : s1;
            acc = __builtin_amdgcn_mfma_f32_16x16x32_bf16(qh0, kh0, acc, 0, 0, 0);
            acc = __builtin_amdgcn_mfma_f32_16x16x32_bf16(qh1, kh1, acc, 0, 0, 0);
            acc = __builtin_amdgcn_mfma_f32_16x16x32_bf16(qh0, kl0, acc, 0, 0, 0);
            acc = __builtin_amdgcn_mfma_f32_16x16x32_bf16(qh1, kl1, acc, 0, 0, 0);
            acc = __builtin_amdgcn_mfma_f32_16x16x32_bf16(ql0, kh0, acc, 0, 0, 0);
            acc = __builtin_amdgcn_mfma_f32_16x16x32_bf16(ql1, kh1, acc, 0, 0, 0);
            if (t == 0) s0 = acc; else s1 = acc;
        }

        // ---- online softmax (row r = quad*4 + reg, col = lrow) ----
        bool v0 = (kb + lrow) < Tt;
        bool v1 = (kb + 16 + lrow) < Tt;
        float alpha_r[4];
#pragma unroll
        for (int r = 0; r < 4; ++r) {
            float a0 = v0 ? s0[r] : -1e30f;
            float a1 = v1 ? s1[r] : -1e30f;
            float mt = fmaxf(a0, a1);
            mt = fmaxf(mt, __shfl_xor(mt, 1));
            mt = fmaxf(mt, __shfl_xor(mt, 2));
            mt = fmaxf(mt, __shfl_xor(mt, 4));
            mt = fmaxf(mt, __shfl_xor(mt, 8));
            float mnew = fmaxf(m_i[r], mt);
            float alpha = __expf(m_i[r] - mnew);
            float p0 = __expf(a0 - mnew);
            float p1 = __expf(a1 - mnew);
            float rs = p0 + p1;
            rs += __shfl_xor(rs, 1);
            rs += __shfl_xor(rs, 2);
            rs += __shfl_xor(rs, 4);
            rs += __shfl_xor(rs, 8);
            l_i[r] = l_i[r] * alpha + rs;
            m_i[r] = mnew;
            alpha_r[r] = alpha;
            int row = quad * 4 + r;
            PB[w][row][lrow]      = f2bf(p0);
            PB[w][row][16 + lrow] = f2bf(p1);
        }

        // ---- P·V: read P A-frag (32 keys), V B-frags over 4 d-tiles ----
        bf16x8 pf = *(const bf16x8*)&PB[w][lrow][quad * 8];
#pragma unroll
        for (int dt = 0; dt < 4; ++dt) {
            bf16x8 vf = *(const bf16x8*)&VT[dt * 16 + lrow][quad * 8];
            f32x4 o = accO[dt];
#pragma unroll
            for (int r = 0; r < 4; ++r) o[r] *= alpha_r[r];
            accO[dt] = __builtin_amdgcn_mfma_f32_16x16x32_bf16(pf, vf, o, 0, 0, 0);
        }
    }

    // ---- epilogue ----
    float il[4];
#pragma unroll
    for (int r = 0; r < 4; ++r) il[r] = 1.f / l_i[r];
#pragma unroll
    for (int dt = 0; dt < 4; ++dt)
#pragma unroll
        for (int r = 0; r < 4; ++r) {
            int qrow = qbase + w * 16 + quad * 4 + r;
            if (qrow < Tt)
                out[(size_t)(c * Tt + qrow) * Dm + h * HD + dt * 16 + lrow] =
                    accO[dt][r] * il[r];
        }
}

// ---------------- kernel 5: scatter/average back to sequence -------------------
__global__ __launch_bounds__(256) void scatter_emb(
    const float* __restrict__ proj, float* __restrict__ emb) {
    int idx = blockIdx.x * 256 + threadIdx.x;
    int row = idx >> 8, c4 = (idx & 255) * 4;
    float4 o;
    if (row < SEQ_TXT) {
        int c = row / TXT, t = row - c * TXT;
        o = *(const float4*)(proj + (size_t)(c * Tt + t) * Dm + c4);
    } else {
        int p = row - SEQ_TXT;
        float sx = 0.f, sy = 0.f, sz = 0.f, sw = 0.f; int cnt = 0;
#pragma unroll
        for (int c = 0; c < CHUNKS; ++c) {
            int off = p - c * STRIDE_V;
            if (off >= 0 && off < CHUNK_VID) {
                float4 x = *(const float4*)(proj + (size_t)(c * Tt + TXT + off) * Dm + c4);
                sx += x.x; sy += x.y; sz += x.z; sw += x.w; ++cnt;
            }
        }
        float inv = 1.f / (float)cnt;
        o = make_float4(sx * inv, sy * inv, sz * inv, sw * inv);
    }
    *(float4*)(emb + (size_t)row * Dm + c4) = o;
}

// ---------------- SSM scan (3-pass segmented) ----------------------------------
__global__ __launch_bounds__(256) void scan_carry(
    const float* __restrict__ u, const float* __restrict__ gate,
    float* __restrict__ carry, int perm) {
    int ch = blockIdx.x * 256 + threadIdx.x;
    int seg = blockIdx.y;
    float g = 1.f / (1.f + expf(-gate[ch]));
    int t0 = seg * SEGL, t1 = min(SEQm, t0 + SEGL);
    float hv = 0.f;
    for (int t = t0; t < t1; ++t) {
        int rt = perm ? rev_map(t) : t;
        hv = fmaf(g, hv, u[(size_t)rt * Dm + ch]);
    }
    carry[(size_t)seg * Dm + ch] = hv;
}

__global__ __launch_bounds__(256) void scan_combine(
    const float* __restrict__ carry, const float* __restrict__ gate,
    float* __restrict__ inc) {
    int ch = blockIdx.x * 256 + threadIdx.x;
    float g = 1.f / (1.f + expf(-gate[ch]));
    float gl = powf(g, (float)SEGL);
    float S = 0.f;
    for (int s = 0; s < NSEG; ++s) {
        inc[(size_t)s * Dm + ch] = S;
        int len = min(SEGL, SEQm - s * SEGL);
        float A = (len == SEGL) ? gl : powf(g, (float)len);
        S = fmaf(A, S, carry[(size_t)s * Dm + ch]);
    }
}

__global__ __launch_bounds__(256) void scan_final(
    const float* __restrict__ u, const float* __restrict__ gate,
    const float* __restrict__ inc, float* __restrict__ hbuf, int perm) {
    int ch = blockIdx.x * 256 + threadIdx.x;
    int seg = blockIdx.y;
    float g = 1.f / (1.f + expf(-gate[ch]));
    int t0 = seg * SEGL, t1 = min(SEQm, t0 + SEGL);
    float hv = inc[(size_t)seg * Dm + ch];
    for (int t = t0; t < t1; ++t) {
        int rt = perm ? rev_map(t) : t;
        hv = fmaf(g, hv, u[(size_t)rt * Dm + ch]);
        hbuf[(size_t)rt * Dm + ch] = hv;
    }
}

// ---------------- elementwise combines -----------------------------------------
__global__ __launch_bounds__(256) void combine1(
    const float* __restrict__ emb, const float* __restrict__ y,
    const float* __restrict__ fg_t, const float* __restrict__ fg_v,
    float* __restrict__ emb2) {
    int idx = blockIdx.x * 256 + threadIdx.x;
    int row = idx >> 8, c4 = (idx & 255) * 4;
    const float* fg = (row < SEQ_TXT) ? fg_t : fg_v;
    float4 e = *(const float4*)(emb + (size_t)row * Dm + c4);
    float4 yy = *(const float4*)(y + (size_t)row * Dm + c4);
    float4 o = make_float4(e.x + tanhf(fg[c4 + 0]) * yy.x,
                           e.y + tanhf(fg[c4 + 1]) * yy.y,
                           e.z + tanhf(fg[c4 + 2]) * yy.z,
                           e.w + tanhf(fg[c4 + 3]) * yy.w);
    *(float4*)(emb2 + (size_t)row * Dm + c4) = o;
}

__global__ __launch_bounds__(256) void final_combine(
    const float* __restrict__ emb2, const float* __restrict__ y2,
    const float* __restrict__ bg_t, const float* __restrict__ bg_v,
    float* __restrict__ outp) {
    int idx = blockIdx.x * 256 + threadIdx.x;
    int row = idx >> 8, c4 = (idx & 255) * 4;
    const float* bg = (row < SEQ_TXT) ? bg_t : bg_v;
    int drow = (row >= SEQ_TXT) ? (row - SEQ_TXT) : (VID_LEN + row);
    float4 e = *(const float4*)(emb2 + (size_t)row * Dm + c4);
    float4 yy = *(const float4*)(y2 + (size_t)row * Dm + c4);
    float4 o = make_float4(e.x + tanhf(bg[c4 + 0]) * yy.x,
                           e.y + tanhf(bg[c4 + 1]) * yy.y,
                           e.z + tanhf(bg[c4 + 2]) * yy.z,
                           e.w + tanhf(bg[c4 + 3]) * yy.w);
    *(float4*)(outp + (size_t)drow * Dm + c4) = o;
}

// ---------------- host-side orchestration --------------------------------------
extern "C" void kernel_launch(void* const* d_in, const int* in_sizes, int n_in,
                              void* d_out, int out_size, void* d_ws, size_t ws_size,
                              hipStream_t stream) {
    const float* vid_emb = (const float*)d_in[0];
    const float* text_emb= (const float*)d_in[1];
    const float* Wq = (const float*)d_in[2];  const float* bq = (const float*)d_in[3];
    const float* Wk = (const float*)d_in[4];  const float* bk = (const float*)d_in[5];
    const float* Wv = (const float*)d_in[6];  const float* bv = (const float*)d_in[7];
    const float* Wo = (const float*)d_in[8];  const float* bo = (const float*)d_in[9];
    const float* qn_w = (const float*)d_in[10]; const float* qn_b = (const float*)d_in[11];
    const float* kn_w = (const float*)d_in[12]; const float* kn_b = (const float*)d_in[13];
    const float* Win  = (const float*)d_in[14]; const float* Wout = (const float*)d_in[15];
    const float* gate = (const float*)d_in[16];
    const float* fg_t = (const float*)d_in[17]; const float* fg_v = (const float*)d_in[18];
    const float* bg_t = (const float*)d_in[19]; const float* bg_v = (const float*)d_in[20];

    // workspace layout (floats)
    const size_t R1 = 0;                       // 5,120,000 : cur -> attn_out -> emb
    const size_t R2 = 5120000;                 // 15,360,000: q/k/v_pre -> u,h,y
    const size_t R3 = 20480000;                // 15,360,000: bf16 planes -> proj -> emb2
    const size_t R4 = 35840000;                // carries
    const size_t need = (size_t)(35840000 + 2 * NSEG * Dm) * sizeof(float);
    if (ws_size < need) return;

    float* ws   = (float*)d_ws;
    float* cur  = ws + R1;
    float* qpre = ws + R2;
    float* kpre = ws + R2 + 5120000;
    float* vpre = ws + R2 + 10240000;
    // bf16 planes in R3 (5 x 5,120,000 ushorts = 12.8M float-equivalents)
    ushort* qhiP = (ushort*)(ws + R3);
    ushort* qloP = qhiP + 5120000;
    ushort* khiP = qhiP + 10240000;
    ushort* kloP = qhiP + 15360000;
    ushort* vbP  = qhiP + 20480000;
    float* attn_out = ws + R1;                 // over dead cur
    float* proj = ws + R3;                     // over dead bf16 planes
    float* emb  = ws + R1;                     // over dead attn_out
    float* u    = ws + R2;                     // over dead qpre
    float* hbuf = ws + R2 + 4333568;
    float* ybuf = ws + R2 + 8667136;
    float* emb2 = ws + R3;                     // over dead proj
    float* carry= ws + R4;
    float* incb = ws + R4 + (size_t)NSEG * Dm;
    float* outp = (float*)d_out;

    build_cur<<<M_QKV, 256, 0, stream>>>(vid_emb, text_emb, cur);

    dim3 gq(16, (M_QKV + 63) / 64);
    gemm_fp32<<<gq, 256, 0, stream>>>(cur, Wq, bq, qpre, M_QKV);
    gemm_fp32<<<gq, 256, 0, stream>>>(cur, Wk, bk, kpre, M_QKV);
    gemm_fp32<<<gq, 256, 0, stream>>>(cur, Wv, bv, vpre, M_QKV);

    lnrope<<<(M_QKV * Hh) / 4, 256, 0, stream>>>(qpre, kpre, vpre, qn_w, qn_b,
                                                 kn_w, kn_b, qhiP, qloP, khiP, kloP, vbP);

    dim3 ga((Tt + 63) / 64, CHUNKS * Hh);
    attn_mfma<<<ga, 256, 0, stream>>>(qhiP, qloP, khiP, kloP, vbP, attn_out);

    gemm_fp32<<<gq, 256, 0, stream>>>(attn_out, Wo, bo, proj, M_QKV);

    scatter_emb<<<SEQm, 256, 0, stream>>>(proj, emb);

    dim3 gu(16, (SEQm + 63) / 64);
    dim3 gscan(Dm / 256, NSEG);

    // SSM forward
    gemm_fp32<<<gu, 256, 0, stream>>>(emb, Win, nullptr, u, SEQm);
    scan_carry<<<gscan, 256, 0, stream>>>(u, gate, carry, 0);
    scan_combine<<<Dm / 256, 256, 0, stream>>>(carry, gate, incb);
    scan_final<<<gscan, 256, 0, stream>>>(u, gate, incb, hbuf, 0);
    gemm_fp32<<<gu, 256, 0, stream>>>(hbuf, Wout, nullptr, ybuf, SEQm);
    combine1<<<SEQm, 256, 0, stream>>>(emb, ybuf, fg_t, fg_v, emb2);

    // SSM backward (permuted scan; GEMMs commute with row permutation)
    gemm_fp32<<<gu, 256, 0, stream>>>(emb2, Win, nullptr, u, SEQm);
    scan_carry<<<gscan, 256, 0, stream>>>(u, gate, carry, 1);
    scan_combine<<<Dm / 256, 256, 0, stream>>>(carry, gate, incb);
    scan_final<<<gscan, 256, 0, stream>>>(u, gate, incb, hbuf, 1);
    gemm_fp32<<<gu, 256, 0, stream>>>(hbuf, Wout, nullptr, ybuf, SEQm);

    final_combine<<<SEQm, 256, 0, stream>>>(emb2, ybuf, bg_t, bg_v, outp);
}

// Round 3
// 924.356 us; speedup vs baseline: 2.6647x; 1.8228x over previous
//
#include <hip/hip_runtime.h>
#include <cstdint>

// ---------------- problem constants ----------------
constexpr int Dm       = 1024;
constexpr int Hh       = 16;
constexpr int HD       = 64;
constexpr int CHUNKS   = 4;
constexpr int TXT      = 226;
constexpr int SEQ_TXT  = 904;        // CHUNKS*TXT
constexpr int VID_LEN  = 3328;       // FRAMES*TPF
constexpr int CHUNK_VID= 1024;       // (PREFIX+ATTN)*TPF
constexpr int Tt       = 1250;       // TXT + CHUNK_VID
constexpr int M_QKV    = 5000;       // CHUNKS*Tt
constexpr int SEQm     = 4232;       // SEQ_TXT + VID_LEN
constexpr int STRIDE_V = 768;        // ATTN*TPF
constexpr float EPSc   = 1e-6f;
constexpr float SCALEc = 0.125f;     // 1/sqrt(64)
constexpr float THETAc = 10000.f;

constexpr int SEGL = 128;
constexpr int NSEG = (SEQm + SEGL - 1) / SEGL;   // 34

typedef __attribute__((ext_vector_type(8))) short bf16x8;
typedef __attribute__((ext_vector_type(4))) float f32x4;

__device__ __forceinline__ ushort f2bf(float x) {
    uint32_t u = __float_as_uint(x);
    u += 0x7FFFu + ((u >> 16) & 1u);
    return (ushort)(u >> 16);
}
__device__ __forceinline__ float bf2f(ushort b) {
    return __uint_as_float(((uint32_t)b) << 16);
}

// async global->LDS, 16B per lane. LDS dest = wave-uniform base + lane*16.
__device__ __forceinline__ void gload_lds16(const ushort* g, ushort* l) {
    __builtin_amdgcn_global_load_lds(
        (const __attribute__((address_space(1))) unsigned int*)g,
        (__attribute__((address_space(3))) unsigned int*)l, 16, 0, 0);
}

// reversal mapping (involution): text chunks flipped, video flipped
__device__ __forceinline__ int rev_map(int i) {
    if (i < SEQ_TXT) {
        int c = i / TXT, o = i - c * TXT;
        return (CHUNKS - 1 - c) * TXT + o;
    }
    int j = i - SEQ_TXT;
    return SEQ_TXT + (VID_LEN - 1 - j);
}

// ---------------- weight transpose + bf16 split: T[n][k] = W[k][n] ------------
__global__ __launch_bounds__(256) void conv_w(
    const float* __restrict__ W, ushort* __restrict__ Thi, ushort* __restrict__ Tlo) {
    __shared__ float tile[32][33];
    int k0 = blockIdx.y * 32, n0 = blockIdx.x * 32;
    int j = threadIdx.x & 31, i0 = threadIdx.x >> 5;
#pragma unroll
    for (int i = i0; i < 32; i += 8)
        tile[i][j] = W[(size_t)(k0 + i) * 1024 + n0 + j];
    __syncthreads();
#pragma unroll
    for (int i = i0; i < 32; i += 8) {
        float v = tile[j][i];                    // W[k0+j][n0+i]
        ushort h = f2bf(v);
        size_t o = (size_t)(n0 + i) * 1024 + k0 + j;
        Thi[o] = h;
        Tlo[o] = f2bf(v - bf2f(h));
    }
}

__global__ __launch_bounds__(256) void conv_bias3(
    const float* __restrict__ bq, const float* __restrict__ bk,
    const float* __restrict__ bv, float* __restrict__ b3) {
    int i = blockIdx.x * 256 + threadIdx.x;
    b3[i] = (i < 1024) ? bq[i] : ((i < 2048) ? bk[i - 1024] : bv[i - 2048]);
}

// ---------------- assemble cur as split-bf16 planes [5000][1024] ---------------
__global__ __launch_bounds__(256) void build_cur(
    const float* __restrict__ vid, const float* __restrict__ txt,
    ushort* __restrict__ chi, ushort* __restrict__ clo) {
    int idx = blockIdx.x * 256 + threadIdx.x;
    int row = idx >> 8, c4 = (idx & 255) * 4;
    int c = row / Tt, t = row - c * Tt;
    float4 x;
    if (t < TXT)
        x = *(const float4*)(txt + (size_t)(c * TXT + t) * Dm + c4);
    else
        x = *(const float4*)(vid + (size_t)(c * STRIDE_V + (t - TXT)) * Dm + c4);
    float v[4] = {x.x, x.y, x.z, x.w};
    ushort4 h, l;
    h.x = f2bf(v[0]); l.x = f2bf(v[0] - bf2f(h.x));
    h.y = f2bf(v[1]); l.y = f2bf(v[1] - bf2f(h.y));
    h.z = f2bf(v[2]); l.z = f2bf(v[2] - bf2f(h.z));
    h.w = f2bf(v[3]); l.w = f2bf(v[3] - bf2f(h.w));
    *(ushort4*)(chi + (size_t)row * Dm + c4) = h;
    *(ushort4*)(clo + (size_t)row * Dm + c4) = l;
}

// ---------------- MFMA GEMM, split-bf16 3-product --------------------------------
// C[M][N] = A[M][1024] @ B[1024][N] + bias.  A given as hi/lo planes [M][1024];
// B given as TRANSPOSED hi/lo planes [N][1024]. Tile 128x64, BK=32, 4 waves.
__global__ __launch_bounds__(256) void gemm_bf16s(
    const ushort* __restrict__ Ahi, const ushort* __restrict__ Alo,
    const ushort* __restrict__ Bhi, const ushort* __restrict__ Blo,
    const float* __restrict__ bias, float* __restrict__ C, int M, int N) {
    __shared__ ushort AH[128 * 32];
    __shared__ ushort AL[128 * 32];
    __shared__ ushort BH[64 * 32];
    __shared__ ushort BL[64 * 32];
    const int tid = threadIdx.x;
    const int w = tid >> 6, lane = tid & 63;
    const int lrow = lane & 15, quad = lane >> 4;
    const int mBase = blockIdx.y * 128, nBase = blockIdx.x * 64;
    const int srow = lane >> 2, schunk = lane & 3;   // staging: 16 rows x 4 chunks

    // precompute per-unit staging pointers (6 units/wave, 24 total):
    // units 0..15: A planes (0..7 = AH rowblocks, 8..15 = AL); 16..23: B planes.
    const ushort* gbase[6];
    ushort* lbase[6];
#pragma unroll
    for (int u = 0; u < 6; ++u) {
        int unit = w * 6 + u;
        if (unit < 16) {
            int rb = unit & 7;
            int r = min(mBase + rb * 16 + srow, M - 1);
            const ushort* P = (unit < 8) ? Ahi : Alo;
            gbase[u] = P + (size_t)r * 1024 + schunk * 8;
            lbase[u] = ((unit < 8) ? AH : AL) + rb * 512;
        } else {
            int t2 = unit - 16;
            int rb = t2 & 3;
            int r = nBase + rb * 16 + srow;
            const ushort* P = (t2 < 4) ? Bhi : Blo;
            gbase[u] = P + (size_t)r * 1024 + schunk * 8;
            lbase[u] = ((t2 < 4) ? BH : BL) + rb * 512;
        }
    }

    const int mo = (w >> 1) * 64, no = (w & 1) * 32;
    f32x4 acc[4][2];
#pragma unroll
    for (int i = 0; i < 4; ++i)
#pragma unroll
        for (int j = 0; j < 2; ++j) acc[i][j] = (f32x4){0.f, 0.f, 0.f, 0.f};

    for (int kk = 0; kk < 1024; kk += 32) {
        __syncthreads();
#pragma unroll
        for (int u = 0; u < 6; ++u) gload_lds16(gbase[u] + kk, lbase[u]);
        __syncthreads();

        bf16x8 ah[4], al[4], bh[2], bl[2];
#pragma unroll
        for (int i = 0; i < 4; ++i) {
            ah[i] = *(const bf16x8*)&AH[(mo + i * 16 + lrow) * 32 + quad * 8];
            al[i] = *(const bf16x8*)&AL[(mo + i * 16 + lrow) * 32 + quad * 8];
        }
#pragma unroll
        for (int j = 0; j < 2; ++j) {
            bh[j] = *(const bf16x8*)&BH[(no + j * 16 + lrow) * 32 + quad * 8];
            bl[j] = *(const bf16x8*)&BL[(no + j * 16 + lrow) * 32 + quad * 8];
        }
#pragma unroll
        for (int i = 0; i < 4; ++i)
#pragma unroll
            for (int j = 0; j < 2; ++j) {
                f32x4 a = acc[i][j];
                a = __builtin_amdgcn_mfma_f32_16x16x32_bf16(ah[i], bh[j], a, 0, 0, 0);
                a = __builtin_amdgcn_mfma_f32_16x16x32_bf16(al[i], bh[j], a, 0, 0, 0);
                a = __builtin_amdgcn_mfma_f32_16x16x32_bf16(ah[i], bl[j], a, 0, 0, 0);
                acc[i][j] = a;
            }
    }

#pragma unroll
    for (int i = 0; i < 4; ++i)
#pragma unroll
        for (int j = 0; j < 2; ++j) {
            int col = nBase + no + j * 16 + lrow;
            float bv = bias ? bias[col] : 0.f;
#pragma unroll
            for (int r = 0; r < 4; ++r) {
                int row = mBase + mo + i * 16 + quad * 4 + r;
                if (row < M) C[(size_t)row * N + col] = acc[i][j][r] + bv;
            }
        }
}

// ---------------- per-head LayerNorm + RoPE3D, split-bf16 relayout ------------
// in : qkvpre [5000][3072] fused (q|k|v each 1024 wide)
__global__ __launch_bounds__(256) void lnrope(
    const float* __restrict__ qkvpre,
    const float* __restrict__ qn_w, const float* __restrict__ qn_b,
    const float* __restrict__ kn_w, const float* __restrict__ kn_b,
    ushort* __restrict__ qhi, ushort* __restrict__ qlo,
    ushort* __restrict__ khi, ushort* __restrict__ klo,
    ushort* __restrict__ vb) {
    int wid  = blockIdx.x * 4 + (threadIdx.x >> 6);
    int lane = threadIdx.x & 63;
    int h = wid & 15, row = wid >> 4;
    int c = row / Tt, t = row - c * Tt;
    size_t src = (size_t)row * 3072 + h * HD + lane;
    float qv = qkvpre[src], kv = qkvpre[src + 1024], vv = qkvpre[src + 2048];

    auto wsum = [](float x) {
#pragma unroll
        for (int o = 32; o; o >>= 1) x += __shfl_xor(x, o);
        return x;
    };
    float qmu = wsum(qv) * (1.f / 64.f);
    float qd  = qv - qmu;
    float qvar = wsum(qd * qd) * (1.f / 64.f);
    float qn = qd * rsqrtf(qvar + EPSc) * qn_w[lane] + qn_b[lane];

    float kmu = wsum(kv) * (1.f / 64.f);
    float kd  = kv - kmu;
    float kvar = wsum(kd * kd) * (1.f / 64.f);
    float kn = kd * rsqrtf(kvar + EPSc) * kn_w[lane] + kn_b[lane];

    if (t >= TXT) {
        int pos = t - TXT;
        int f = pos >> 8, rem = pos & 255, hp = rem >> 4, wp = rem & 15;
        int dim, p, dl;
        if (lane < 16)      { dim = 16; p = f;  dl = lane; }
        else if (lane < 40) { dim = 24; p = hp; dl = lane - 16; }
        else                { dim = 24; p = wp; dl = lane - 40; }
        int half = dim >> 1;
        int i = (dl < half) ? dl : dl - half;
        float ang = (float)p * powf(THETAc, -2.0f * (float)i / (float)dim);
        float cs = cosf(ang), sn = sinf(ang);
        int partner = (dl < half) ? (lane + half) : (lane - half);
        float qo = __shfl(qn, partner);
        float ko = __shfl(kn, partner);
        qn = (dl < half) ? (qn * cs - qo * sn) : (qo * sn + qn * cs);
        kn = (dl < half) ? (kn * cs - ko * sn) : (ko * sn + kn * cs);
    }
    size_t dst = ((size_t)(c * Hh + h) * Tt + t) * HD + lane;
    float qs = qn * SCALEc;
    ushort qh = f2bf(qs);
    qhi[dst] = qh;
    qlo[dst] = f2bf(qs - bf2f(qh));
    ushort kh = f2bf(kn);
    khi[dst] = kh;
    klo[dst] = f2bf(kn - bf2f(kh));
    vb[dst]  = f2bf(vv);
}

// ---------------- MFMA flash attention, 64 q rows / block ----------------------
__global__ __launch_bounds__(256) void attn_mfma(
    const ushort* __restrict__ qhi, const ushort* __restrict__ qlo,
    const ushort* __restrict__ khi, const ushort* __restrict__ klo,
    const ushort* __restrict__ vb,
    ushort* __restrict__ ohi, ushort* __restrict__ olo) {
    const int ch = blockIdx.y;                 // c*16 + h
    const int c = ch >> 4, h = ch & 15;
    const int qbase = blockIdx.x * 64;
    const int tid = threadIdx.x, w = tid >> 6, lane = tid & 63;
    const int lrow = lane & 15, quad = lane >> 4;

    __shared__ ushort KH[32][88];
    __shared__ ushort KL[32][88];
    __shared__ ushort VT[64][40];
    __shared__ ushort PB[4][16][40];

    const size_t chb = (size_t)ch * Tt * HD;

    bf16x8 qh0 = {0,0,0,0,0,0,0,0}, qh1 = qh0, ql0 = qh0, ql1 = qh0;
    {
        int qr = qbase + w * 16 + lrow;
        if (qr < Tt) {
            const ushort* p = qhi + chb + (size_t)qr * HD + quad * 8;
            qh0 = *(const bf16x8*)p;
            qh1 = *(const bf16x8*)(p + 32);
            const ushort* p2 = qlo + chb + (size_t)qr * HD + quad * 8;
            ql0 = *(const bf16x8*)p2;
            ql1 = *(const bf16x8*)(p2 + 32);
        }
    }

    f32x4 accO[4];
#pragma unroll
    for (int dt = 0; dt < 4; ++dt) accO[dt] = (f32x4){0.f, 0.f, 0.f, 0.f};
    float m_i[4], l_i[4];
#pragma unroll
    for (int r = 0; r < 4; ++r) { m_i[r] = -1e30f; l_i[r] = 0.f; }

    const int kr = tid >> 3, kc8 = (tid & 7) * 8;

    for (int kb = 0; kb < Tt; kb += 32) {
        int lim = min(32, Tt - kb);
        __syncthreads();
        {
            bf16x8 z = {0,0,0,0,0,0,0,0};
            bf16x8 a = z, b = z;
            if (kb + kr < Tt) {
                a = *(const bf16x8*)(khi + chb + (size_t)(kb + kr) * HD + kc8);
                b = *(const bf16x8*)(klo + chb + (size_t)(kb + kr) * HD + kc8);
            }
            *(bf16x8*)&KH[kr][kc8] = a;
            *(bf16x8*)&KL[kr][kc8] = b;
            short vv[8];
#pragma unroll
            for (int i = 0; i < 8; ++i) {
                int key = kb + w * 8 + i;
                vv[i] = (key < Tt) ? (short)vb[chb + (size_t)key * HD + lane] : (short)0;
            }
            *(bf16x8*)&VT[lane][w * 8] = *(bf16x8*)vv;
        }
        __syncthreads();

        f32x4 s0 = {0.f, 0.f, 0.f, 0.f}, s1 = s0;
#pragma unroll
        for (int t = 0; t < 2; ++t) {
            const ushort* kh = &KH[t * 16 + lrow][quad * 8];
            const ushort* kl = &KL[t * 16 + lrow][quad * 8];
            bf16x8 kh0 = *(const bf16x8*)kh;
            bf16x8 kh1 = *(const bf16x8*)(kh + 32);
            bf16x8 kl0 = *(const bf16x8*)kl;
            bf16x8 kl1 = *(const bf16x8*)(kl + 32);
            f32x4 acc = (t == 0) ? s0 : s1;
            acc = __builtin_amdgcn_mfma_f32_16x16x32_bf16(qh0, kh0, acc, 0, 0, 0);
            acc = __builtin_amdgcn_mfma_f32_16x16x32_bf16(qh1, kh1, acc, 0, 0, 0);
            acc = __builtin_amdgcn_mfma_f32_16x16x32_bf16(qh0, kl0, acc, 0, 0, 0);
            acc = __builtin_amdgcn_mfma_f32_16x16x32_bf16(qh1, kl1, acc, 0, 0, 0);
            acc = __builtin_amdgcn_mfma_f32_16x16x32_bf16(ql0, kh0, acc, 0, 0, 0);
            acc = __builtin_amdgcn_mfma_f32_16x16x32_bf16(ql1, kh1, acc, 0, 0, 0);
            if (t == 0) s0 = acc; else s1 = acc;
        }

        bool v0 = (lrow) < lim;
        bool v1 = (16 + lrow) < lim;
        float alpha_r[4];
#pragma unroll
        for (int r = 0; r < 4; ++r) {
            float a0 = v0 ? s0[r] : -1e30f;
            float a1 = v1 ? s1[r] : -1e30f;
            float mt = fmaxf(a0, a1);
            mt = fmaxf(mt, __shfl_xor(mt, 1));
            mt = fmaxf(mt, __shfl_xor(mt, 2));
            mt = fmaxf(mt, __shfl_xor(mt, 4));
            mt = fmaxf(mt, __shfl_xor(mt, 8));
            float mnew = fmaxf(m_i[r], mt);
            float alpha = __expf(m_i[r] - mnew);
            float p0 = __expf(a0 - mnew);
            float p1 = __expf(a1 - mnew);
            float rs = p0 + p1;
            rs += __shfl_xor(rs, 1);
            rs += __shfl_xor(rs, 2);
            rs += __shfl_xor(rs, 4);
            rs += __shfl_xor(rs, 8);
            l_i[r] = l_i[r] * alpha + rs;
            m_i[r] = mnew;
            alpha_r[r] = alpha;
            int row = quad * 4 + r;
            PB[w][row][lrow]      = f2bf(p0);
            PB[w][row][16 + lrow] = f2bf(p1);
        }

        bf16x8 pf = *(const bf16x8*)&PB[w][lrow][quad * 8];
#pragma unroll
        for (int dt = 0; dt < 4; ++dt) {
            bf16x8 vf = *(const bf16x8*)&VT[dt * 16 + lrow][quad * 8];
            f32x4 o = accO[dt];
#pragma unroll
            for (int r = 0; r < 4; ++r) o[r] *= alpha_r[r];
            accO[dt] = __builtin_amdgcn_mfma_f32_16x16x32_bf16(pf, vf, o, 0, 0, 0);
        }
    }

    float il[4];
#pragma unroll
    for (int r = 0; r < 4; ++r) il[r] = 1.f / l_i[r];
#pragma unroll
    for (int dt = 0; dt < 4; ++dt)
#pragma unroll
        for (int r = 0; r < 4; ++r) {
            int qrow = qbase + w * 16 + quad * 4 + r;
            if (qrow < Tt) {
                float val = accO[dt][r] * il[r];
                size_t o = (size_t)(c * Tt + qrow) * Dm + h * HD + dt * 16 + lrow;
                ushort hv = f2bf(val);
                ohi[o] = hv;
                olo[o] = f2bf(val - bf2f(hv));
            }
        }
}

// ---------------- scatter/average back to sequence; emit fp32 + planes --------
__global__ __launch_bounds__(256) void scatter_emb(
    const float* __restrict__ proj, float* __restrict__ emb,
    ushort* __restrict__ ehi, ushort* __restrict__ elo) {
    int idx = blockIdx.x * 256 + threadIdx.x;
    int row = idx >> 8, c4 = (idx & 255) * 4;
    float4 o;
    if (row < SEQ_TXT) {
        int c = row / TXT, t = row - c * TXT;
        o = *(const float4*)(proj + (size_t)(c * Tt + t) * Dm + c4);
    } else {
        int p = row - SEQ_TXT;
        float sx = 0.f, sy = 0.f, sz = 0.f, sw = 0.f; int cnt = 0;
#pragma unroll
        for (int c = 0; c < CHUNKS; ++c) {
            int off = p - c * STRIDE_V;
            if (off >= 0 && off < CHUNK_VID) {
                float4 x = *(const float4*)(proj + (size_t)(c * Tt + TXT + off) * Dm + c4);
                sx += x.x; sy += x.y; sz += x.z; sw += x.w; ++cnt;
            }
        }
        float inv = 1.f / (float)cnt;
        o = make_float4(sx * inv, sy * inv, sz * inv, sw * inv);
    }
    *(float4*)(emb + (size_t)row * Dm + c4) = o;
    float v[4] = {o.x, o.y, o.z, o.w};
    ushort4 h, l;
    h.x = f2bf(v[0]); l.x = f2bf(v[0] - bf2f(h.x));
    h.y = f2bf(v[1]); l.y = f2bf(v[1] - bf2f(h.y));
    h.z = f2bf(v[2]); l.z = f2bf(v[2] - bf2f(h.z));
    h.w = f2bf(v[3]); l.w = f2bf(v[3] - bf2f(h.w));
    *(ushort4*)(ehi + (size_t)row * Dm + c4) = h;
    *(ushort4*)(elo + (size_t)row * Dm + c4) = l;
}

// ---------------- SSM scan (3-pass segmented) ----------------------------------
__global__ __launch_bounds__(256) void scan_carry(
    const float* __restrict__ u, const float* __restrict__ gate,
    float* __restrict__ carry, int perm) {
    int ch = blockIdx.x * 256 + threadIdx.x;
    int seg = blockIdx.y;
    float g = 1.f / (1.f + expf(-gate[ch]));
    int t0 = seg * SEGL, t1 = min(SEQm, t0 + SEGL);
    float hv = 0.f;
    for (int t = t0; t < t1; ++t) {
        int rt = perm ? rev_map(t) : t;
        hv = fmaf(g, hv, u[(size_t)rt * Dm + ch]);
    }
    carry[(size_t)seg * Dm + ch] = hv;
}

__global__ __launch_bounds__(256) void scan_combine(
    const float* __restrict__ carry, const float* __restrict__ gate,
    float* __restrict__ inc) {
    int ch = blockIdx.x * 256 + threadIdx.x;
    float g = 1.f / (1.f + expf(-gate[ch]));
    float gl = powf(g, (float)SEGL);
    float S = 0.f;
    for (int s = 0; s < NSEG; ++s) {
        inc[(size_t)s * Dm + ch] = S;
        int len = min(SEGL, SEQm - s * SEGL);
        float A = (len == SEGL) ? gl : powf(g, (float)len);
        S = fmaf(A, S, carry[(size_t)s * Dm + ch]);
    }
}

// final scan pass writes h as split-bf16 planes (only consumed by Wout GEMM)
__global__ __launch_bounds__(256) void scan_final(
    const float* __restrict__ u, const float* __restrict__ gate,
    const float* __restrict__ inc,
    ushort* __restrict__ hhi, ushort* __restrict__ hlo, int perm) {
    int ch = blockIdx.x * 256 + threadIdx.x;
    int seg = blockIdx.y;
    float g = 1.f / (1.f + expf(-gate[ch]));
    int t0 = seg * SEGL, t1 = min(SEQm, t0 + SEGL);
    float hv = inc[(size_t)seg * Dm + ch];
    for (int t = t0; t < t1; ++t) {
        int rt = perm ? rev_map(t) : t;
        hv = fmaf(g, hv, u[(size_t)rt * Dm + ch]);
        ushort h = f2bf(hv);
        hhi[(size_t)rt * Dm + ch] = h;
        hlo[(size_t)rt * Dm + ch] = f2bf(hv - bf2f(h));
    }
}

// ---------------- elementwise combines -----------------------------------------
__global__ __launch_bounds__(256) void combine1(
    const float* __restrict__ emb, const float* __restrict__ y,
    const float* __restrict__ fg_t, const float* __restrict__ fg_v,
    float* __restrict__ emb2, ushort* __restrict__ e2hi, ushort* __restrict__ e2lo) {
    int idx = blockIdx.x * 256 + threadIdx.x;
    int row = idx >> 8, c4 = (idx & 255) * 4;
    const float* fg = (row < SEQ_TXT) ? fg_t : fg_v;
    float4 e = *(const float4*)(emb + (size_t)row * Dm + c4);
    float4 yy = *(const float4*)(y + (size_t)row * Dm + c4);
    float v[4];
    v[0] = e.x + tanhf(fg[c4 + 0]) * yy.x;
    v[1] = e.y + tanhf(fg[c4 + 1]) * yy.y;
    v[2] = e.z + tanhf(fg[c4 + 2]) * yy.z;
    v[3] = e.w + tanhf(fg[c4 + 3]) * yy.w;
    *(float4*)(emb2 + (size_t)row * Dm + c4) = make_float4(v[0], v[1], v[2], v[3]);
    ushort4 h, l;
    h.x = f2bf(v[0]); l.x = f2bf(v[0] - bf2f(h.x));
    h.y = f2bf(v[1]); l.y = f2bf(v[1] - bf2f(h.y));
    h.z = f2bf(v[2]); l.z = f2bf(v[2] - bf2f(h.z));
    h.w = f2bf(v[3]); l.w = f2bf(v[3] - bf2f(h.w));
    *(ushort4*)(e2hi + (size_t)row * Dm + c4) = h;
    *(ushort4*)(e2lo + (size_t)row * Dm + c4) = l;
}

__global__ __launch_bounds__(256) void final_combine(
    const float* __restrict__ emb2, const float* __restrict__ y2,
    const float* __restrict__ bg_t, const float* __restrict__ bg_v,
    float* __restrict__ outp) {
    int idx = blockIdx.x * 256 + threadIdx.x;
    int row = idx >> 8, c4 = (idx & 255) * 4;
    const float* bg = (row < SEQ_TXT) ? bg_t : bg_v;
    int drow = (row >= SEQ_TXT) ? (row - SEQ_TXT) : (VID_LEN + row);
    float4 e = *(const float4*)(emb2 + (size_t)row * Dm + c4);
    float4 yy = *(const float4*)(y2 + (size_t)row * Dm + c4);
    float4 o = make_float4(e.x + tanhf(bg[c4 + 0]) * yy.x,
                           e.y + tanhf(bg[c4 + 1]) * yy.y,
                           e.z + tanhf(bg[c4 + 2]) * yy.z,
                           e.w + tanhf(bg[c4 + 3]) * yy.w);
    *(float4*)(outp + (size_t)drow * Dm + c4) = o;
}

// ---------------- host-side orchestration --------------------------------------
extern "C" void kernel_launch(void* const* d_in, const int* in_sizes, int n_in,
                              void* d_out, int out_size, void* d_ws, size_t ws_size,
                              hipStream_t stream) {
    const float* vid_emb = (const float*)d_in[0];
    const float* text_emb= (const float*)d_in[1];
    const float* Wq = (const float*)d_in[2];  const float* bq = (const float*)d_in[3];
    const float* Wk = (const float*)d_in[4];  const float* bk = (const float*)d_in[5];
    const float* Wv = (const float*)d_in[6];  const float* bv = (const float*)d_in[7];
    const float* Wo = (const float*)d_in[8];  const float* bo = (const float*)d_in[9];
    const float* qn_w = (const float*)d_in[10]; const float* qn_b = (const float*)d_in[11];
    const float* kn_w = (const float*)d_in[12]; const float* kn_b = (const float*)d_in[13];
    const float* Win  = (const float*)d_in[14]; const float* Wout = (const float*)d_in[15];
    const float* gate = (const float*)d_in[16];
    const float* fg_t = (const float*)d_in[17]; const float* fg_v = (const float*)d_in[18];
    const float* bg_t = (const float*)d_in[19]; const float* bg_v = (const float*)d_in[20];

    // ---- workspace layout (byte offsets; lifetimes verified non-overlapping) ----
    char* W8 = (char*)d_ws;
    if (ws_size < 137818112u) return;
    ushort* WqkvH = (ushort*)(W8 + 0);            // [3072][1024]
    ushort* WqkvL = (ushort*)(W8 + 6291456);
    ushort* WoH   = (ushort*)(W8 + 12582912);     // [1024][1024] each
    ushort* WoL   = (ushort*)(W8 + 14680064);
    ushort* WinH  = (ushort*)(W8 + 16777216);
    ushort* WinL  = (ushort*)(W8 + 18874368);
    ushort* WoutH = (ushort*)(W8 + 20971520);
    ushort* WoutL = (ushort*)(W8 + 23068672);
    float*  b3    = (float*) (W8 + 25165824);     // [3072]
    ushort* curH  = (ushort*)(W8 + 25178112);     // [5000][1024]
    ushort* curL  = (ushort*)(W8 + 35418112);
    float*  qkvpre= (float*) (W8 + 45658112);     // [5000][3072]
    ushort* qhiP  = (ushort*)(W8 + 25178112);     // over dead cur planes
    ushort* qloP  = (ushort*)(W8 + 35418112);
    ushort* khiP  = (ushort*)(W8 + 107098112);
    ushort* kloP  = (ushort*)(W8 + 117338112);
    ushort* vbP   = (ushort*)(W8 + 127578112);
    ushort* aoutH = (ushort*)(W8 + 45658112);     // over dead qkvpre
    ushort* aoutL = (ushort*)(W8 + 55898112);
    float*  proj  = (float*) (W8 + 66138112);     // [5000][1024]
    float*  emb   = (float*) (W8 + 25178112);     // over dead q planes
    ushort* embH  = (ushort*)(W8 + 86618112);
    ushort* embL  = (ushort*)(W8 + 95285248);
    float*  u1    = (float*) (W8 + 103952384);    // [4232][1024]
    ushort* hbufH = (ushort*)(W8 + 45658112);     // over dead aout
    ushort* hbufL = (ushort*)(W8 + 54325248);
    float*  ybuf  = (float*) (W8 + 62992384);
    float*  emb2  = (float*) (W8 + 80326656);
    ushort* e2H   = (ushort*)(W8 + 97660928);
    ushort* e2L   = (ushort*)(W8 + 106328064);
    float*  u2    = (float*) (W8 + 114995200);
    float*  carry = (float*) (W8 + 132329472);
    float*  incb  = (float*) (W8 + 132468736);
    float*  outp  = (float*)d_out;

    // ---- weight conversion (transpose + split) ----
    dim3 gw(32, 32);
    conv_w<<<gw, 256, 0, stream>>>(Wq, WqkvH, WqkvL);
    conv_w<<<gw, 256, 0, stream>>>(Wk, WqkvH + 1024 * 1024, WqkvL + 1024 * 1024);
    conv_w<<<gw, 256, 0, stream>>>(Wv, WqkvH + 2 * 1024 * 1024, WqkvL + 2 * 1024 * 1024);
    conv_w<<<gw, 256, 0, stream>>>(Wo, WoH, WoL);
    conv_w<<<gw, 256, 0, stream>>>(Win, WinH, WinL);
    conv_w<<<gw, 256, 0, stream>>>(Wout, WoutH, WoutL);
    conv_bias3<<<12, 256, 0, stream>>>(bq, bk, bv, b3);

    build_cur<<<M_QKV, 256, 0, stream>>>(vid_emb, text_emb, curH, curL);

    // fused QKV GEMM: [5000][3072]
    gemm_bf16s<<<dim3(48, 40), 256, 0, stream>>>(curH, curL, WqkvH, WqkvL, b3,
                                                 qkvpre, M_QKV, 3072);

    lnrope<<<(M_QKV * Hh) / 4, 256, 0, stream>>>(qkvpre, qn_w, qn_b, kn_w, kn_b,
                                                 qhiP, qloP, khiP, kloP, vbP);

    dim3 ga((Tt + 63) / 64, CHUNKS * Hh);
    attn_mfma<<<ga, 256, 0, stream>>>(qhiP, qloP, khiP, kloP, vbP, aoutH, aoutL);

    gemm_bf16s<<<dim3(16, 40), 256, 0, stream>>>(aoutH, aoutL, WoH, WoL, bo,
                                                 proj, M_QKV, 1024);

    scatter_emb<<<SEQm, 256, 0, stream>>>(proj, emb, embH, embL);

    dim3 gsq(16, 34);
    dim3 gscan(Dm / 256, NSEG);

    // SSM forward
    gemm_bf16s<<<gsq, 256, 0, stream>>>(embH, embL, WinH, WinL, nullptr, u1, SEQm, 1024);
    scan_carry<<<gscan, 256, 0, stream>>>(u1, gate, carry, 0);
    scan_combine<<<Dm / 256, 256, 0, stream>>>(carry, gate, incb);
    scan_final<<<gscan, 256, 0, stream>>>(u1, gate, incb, hbufH, hbufL, 0);
    gemm_bf16s<<<gsq, 256, 0, stream>>>(hbufH, hbufL, WoutH, WoutL, nullptr, ybuf, SEQm, 1024);
    combine1<<<SEQm, 256, 0, stream>>>(emb, ybuf, fg_t, fg_v, emb2, e2H, e2L);

    // SSM backward (permuted scan; GEMMs commute with row permutation)
    gemm_bf16s<<<gsq, 256, 0, stream>>>(e2H, e2L, WinH, WinL, nullptr, u2, SEQm, 1024);
    scan_carry<<<gscan, 256, 0, stream>>>(u2, gate, carry, 1);
    scan_combine<<<Dm / 256, 256, 0, stream>>>(carry, gate, incb);
    scan_final<<<gscan, 256, 0, stream>>>(u2, gate, incb, hbufH, hbufL, 1);
    gemm_bf16s<<<gsq, 256, 0, stream>>>(hbufH, hbufL, WoutH, WoutL, nullptr, ybuf, SEQm, 1024);

    final_combine<<<SEQm, 256, 0, stream>>>(emb2, ybuf, bg_t, bg_v, outp);
}

// Round 5
// 825.838 us; speedup vs baseline: 2.9826x; 1.1193x over previous
//
#include <hip/hip_runtime.h>
#include <cstdint>

// ---------------- problem constants ----------------
constexpr int Dm       = 1024;
constexpr int Hh       = 16;
constexpr int HD       = 64;
constexpr int CHUNKS   = 4;
constexpr int TXT      = 226;
constexpr int SEQ_TXT  = 904;        // CHUNKS*TXT
constexpr int VID_LEN  = 3328;       // FRAMES*TPF
constexpr int CHUNK_VID= 1024;       // (PREFIX+ATTN)*TPF
constexpr int Tt       = 1250;       // TXT + CHUNK_VID
constexpr int Tp       = 1280;       // padded (multiple of 64), rows >= Tt zeroed
constexpr int M_QKV    = 5000;       // CHUNKS*Tt
constexpr int SEQm     = 4232;       // SEQ_TXT + VID_LEN
constexpr int STRIDE_V = 768;        // ATTN*TPF
constexpr float EPSc   = 1e-6f;
constexpr float SCALEc = 0.125f;     // 1/sqrt(64)
constexpr float THETAc = 10000.f;
constexpr float OFFS   = 8.0f;       // |score| <= 8 by Cauchy-Schwarz (LN'd q,k)

constexpr int SEGL = 128;
constexpr int NSEG = (SEQm + SEGL - 1) / SEGL;   // 34

typedef __attribute__((ext_vector_type(8))) short bf16x8;
typedef __attribute__((ext_vector_type(4))) float f32x4;

__device__ __forceinline__ ushort f2bf(float x) {
    uint32_t u = __float_as_uint(x);
    u += 0x7FFFu + ((u >> 16) & 1u);
    return (ushort)(u >> 16);
}
__device__ __forceinline__ float bf2f(ushort b) {
    return __uint_as_float(((uint32_t)b) << 16);
}

// async global->LDS, 16B/lane. LDS dest = wave-uniform base + lane*16.
__device__ __forceinline__ void gload_lds16(const ushort* g, ushort* l) {
    __builtin_amdgcn_global_load_lds(
        (const __attribute__((address_space(1))) unsigned int*)g,
        (__attribute__((address_space(3))) unsigned int*)l, 16, 0, 0);
}

// reversal mapping (involution): text chunks flipped, video flipped
__device__ __forceinline__ int rev_map(int i) {
    if (i < SEQ_TXT) {
        int c = i / TXT, o = i - c * TXT;
        return (CHUNKS - 1 - c) * TXT + o;
    }
    int j = i - SEQ_TXT;
    return SEQ_TXT + (VID_LEN - 1 - j);
}

// ---------------- weight transpose + bf16 split: T[n][k] = W[k][n] ------------
__global__ __launch_bounds__(256) void conv_w(
    const float* __restrict__ W, ushort* __restrict__ Thi, ushort* __restrict__ Tlo) {
    __shared__ float tile[32][33];
    int k0 = blockIdx.y * 32, n0 = blockIdx.x * 32;
    int j = threadIdx.x & 31, i0 = threadIdx.x >> 5;
#pragma unroll
    for (int i = i0; i < 32; i += 8)
        tile[i][j] = W[(size_t)(k0 + i) * 1024 + n0 + j];
    __syncthreads();
#pragma unroll
    for (int i = i0; i < 32; i += 8) {
        float v = tile[j][i];                    // W[k0+j][n0+i]
        ushort h = f2bf(v);
        size_t o = (size_t)(n0 + i) * 1024 + k0 + j;
        Thi[o] = h;
        Tlo[o] = f2bf(v - bf2f(h));
    }
}

__global__ __launch_bounds__(256) void conv_bias3(
    const float* __restrict__ bq, const float* __restrict__ bk,
    const float* __restrict__ bv, float* __restrict__ b3) {
    int i = blockIdx.x * 256 + threadIdx.x;
    b3[i] = (i < 1024) ? bq[i] : ((i < 2048) ? bk[i - 1024] : bv[i - 2048]);
}

// ---------------- assemble cur as split-bf16 planes [5000][1024] ---------------
__global__ __launch_bounds__(256) void build_cur(
    const float* __restrict__ vid, const float* __restrict__ txt,
    ushort* __restrict__ chi, ushort* __restrict__ clo) {
    int idx = blockIdx.x * 256 + threadIdx.x;
    int row = idx >> 8, c4 = (idx & 255) * 4;
    int c = row / Tt, t = row - c * Tt;
    float4 x;
    if (t < TXT)
        x = *(const float4*)(txt + (size_t)(c * TXT + t) * Dm + c4);
    else
        x = *(const float4*)(vid + (size_t)(c * STRIDE_V + (t - TXT)) * Dm + c4);
    float v[4] = {x.x, x.y, x.z, x.w};
    ushort4 h, l;
    h.x = f2bf(v[0]); l.x = f2bf(v[0] - bf2f(h.x));
    h.y = f2bf(v[1]); l.y = f2bf(v[1] - bf2f(h.y));
    h.z = f2bf(v[2]); l.z = f2bf(v[2] - bf2f(h.z));
    h.w = f2bf(v[3]); l.w = f2bf(v[3] - bf2f(h.w));
    *(ushort4*)(chi + (size_t)row * Dm + c4) = h;
    *(ushort4*)(clo + (size_t)row * Dm + c4) = l;
}

// ---------------- MFMA GEMM, split-bf16 3-product, 128x128 tile ----------------
// C[M][N] = A[M][1024] @ B[1024][N] + bias. A as hi/lo planes [M][1024];
// B as TRANSPOSED hi/lo planes [N][1024]. BK=32, 4 waves, wave-tile 64x64.
__global__ __launch_bounds__(256) void gemm_bf16s(
    const ushort* __restrict__ Ahi, const ushort* __restrict__ Alo,
    const ushort* __restrict__ Bhi, const ushort* __restrict__ Blo,
    const float* __restrict__ bias, float* __restrict__ C, int M, int N) {
    __shared__ ushort AH[128 * 32];
    __shared__ ushort AL[128 * 32];
    __shared__ ushort BH[128 * 32];
    __shared__ ushort BL[128 * 32];
    const int tid = threadIdx.x;
    const int w = tid >> 6, lane = tid & 63;
    const int lrow = lane & 15, quad = lane >> 4;
    const int mBase = blockIdx.y * 128, nBase = blockIdx.x * 128;
    const int srow = lane >> 2, schunk = lane & 3;

    // wave w stages one whole plane (8 rowblocks of 16 rows)
    const ushort* gplane = (w == 0) ? Ahi : (w == 1) ? Alo : (w == 2) ? Bhi : Blo;
    ushort* lplane = (w == 0) ? AH : (w == 1) ? AL : (w == 2) ? BH : BL;
    const int base = (w < 2) ? mBase : nBase;
    const int maxr = (w < 2) ? (M - 1) : (N - 1);
    const ushort* gb[8];
#pragma unroll
    for (int rb = 0; rb < 8; ++rb) {
        int r = min(base + rb * 16 + srow, maxr);
        gb[rb] = gplane + (size_t)r * 1024 + schunk * 8;
    }

    const int mo = (w >> 1) * 64, no = (w & 1) * 64;
    f32x4 acc[4][4];
#pragma unroll
    for (int i = 0; i < 4; ++i)
#pragma unroll
        for (int j = 0; j < 4; ++j) acc[i][j] = (f32x4){0.f, 0.f, 0.f, 0.f};

    for (int kk = 0; kk < 1024; kk += 32) {
        __syncthreads();
#pragma unroll
        for (int rb = 0; rb < 8; ++rb) gload_lds16(gb[rb] + kk, lplane + rb * 512);
        __syncthreads();

        bf16x8 ah[4], al[4], bh[4], bl[4];
#pragma unroll
        for (int i = 0; i < 4; ++i) {
            ah[i] = *(const bf16x8*)&AH[(mo + i * 16 + lrow) * 32 + quad * 8];
            al[i] = *(const bf16x8*)&AL[(mo + i * 16 + lrow) * 32 + quad * 8];
        }
#pragma unroll
        for (int j = 0; j < 4; ++j) {
            bh[j] = *(const bf16x8*)&BH[(no + j * 16 + lrow) * 32 + quad * 8];
            bl[j] = *(const bf16x8*)&BL[(no + j * 16 + lrow) * 32 + quad * 8];
        }
#pragma unroll
        for (int i = 0; i < 4; ++i)
#pragma unroll
            for (int j = 0; j < 4; ++j) {
                f32x4 a = acc[i][j];
                a = __builtin_amdgcn_mfma_f32_16x16x32_bf16(ah[i], bh[j], a, 0, 0, 0);
                a = __builtin_amdgcn_mfma_f32_16x16x32_bf16(al[i], bh[j], a, 0, 0, 0);
                a = __builtin_amdgcn_mfma_f32_16x16x32_bf16(ah[i], bl[j], a, 0, 0, 0);
                acc[i][j] = a;
            }
    }

#pragma unroll
    for (int i = 0; i < 4; ++i)
#pragma unroll
        for (int j = 0; j < 4; ++j) {
            int col = nBase + no + j * 16 + lrow;
            float bv = bias ? bias[col] : 0.f;
#pragma unroll
            for (int r = 0; r < 4; ++r) {
                int row = mBase + mo + i * 16 + quad * 4 + r;
                if (row < M) C[(size_t)row * N + col] = acc[i][j][r] + bv;
            }
        }
}

// ---------------- per-head LayerNorm + RoPE3D, bf16 planes (padded Tp) --------
// in : qkvpre [5000][3072] fused.  out: qP/kP/vP [64ch][Tp][64] (q pre-scaled)
__global__ __launch_bounds__(256) void lnrope(
    const float* __restrict__ qkvpre,
    const float* __restrict__ qn_w, const float* __restrict__ qn_b,
    const float* __restrict__ kn_w, const float* __restrict__ kn_b,
    ushort* __restrict__ qP, ushort* __restrict__ kP, ushort* __restrict__ vP) {
    int wid  = blockIdx.x * 4 + (threadIdx.x >> 6);
    int lane = threadIdx.x & 63;
    int c = wid / (Hh * Tp);
    int rem = wid - c * (Hh * Tp);
    int h = rem / Tp, t = rem - h * Tp;
    size_t dst = ((size_t)(c * Hh + h) * Tp + t) * HD + lane;
    if (t >= Tt) { qP[dst] = 0; kP[dst] = 0; vP[dst] = 0; return; }
    size_t src = (size_t)(c * Tt + t) * 3072 + h * HD + lane;
    float qv = qkvpre[src], kv = qkvpre[src + 1024], vv = qkvpre[src + 2048];

    auto wsum = [](float x) {
#pragma unroll
        for (int o = 32; o; o >>= 1) x += __shfl_xor(x, o);
        return x;
    };
    float qmu = wsum(qv) * (1.f / 64.f);
    float qd  = qv - qmu;
    float qvar = wsum(qd * qd) * (1.f / 64.f);
    float qn = qd * rsqrtf(qvar + EPSc) * qn_w[lane] + qn_b[lane];

    float kmu = wsum(kv) * (1.f / 64.f);
    float kd  = kv - kmu;
    float kvar = wsum(kd * kd) * (1.f / 64.f);
    float kn = kd * rsqrtf(kvar + EPSc) * kn_w[lane] + kn_b[lane];

    if (t >= TXT) {
        int pos = t - TXT;
        int f = pos >> 8, rem2 = pos & 255, hp = rem2 >> 4, wp = rem2 & 15;
        int dim, p, dl;
        if (lane < 16)      { dim = 16; p = f;  dl = lane; }
        else if (lane < 40) { dim = 24; p = hp; dl = lane - 16; }
        else                { dim = 24; p = wp; dl = lane - 40; }
        int half = dim >> 1;
        int i = (dl < half) ? dl : dl - half;
        float ang = (float)p * powf(THETAc, -2.0f * (float)i / (float)dim);
        float cs = cosf(ang), sn = sinf(ang);
        int partner = (dl < half) ? (lane + half) : (lane - half);
        float qo = __shfl(qn, partner);
        float ko = __shfl(kn, partner);
        qn = (dl < half) ? (qn * cs - qo * sn) : (qo * sn + qn * cs);
        kn = (dl < half) ? (kn * cs - ko * sn) : (ko * sn + kn * cs);
    }
    qP[dst] = f2bf(qn * SCALEc);
    kP[dst] = f2bf(kn);
    vP[dst] = f2bf(vv);
}

// ---------------- V transpose: vT[ch][d][t] = vP[ch][t][d] ---------------------
// 64x64 tile, 256 threads x 16 elements each (full coverage).
__global__ __launch_bounds__(256) void transpose_v(
    const ushort* __restrict__ vP, ushort* __restrict__ vT) {
    __shared__ ushort tile[64][72];              // [key][dim]
    const int ch = blockIdx.y, t0 = blockIdx.x * 64;
    const int tid = threadIdx.x;
    const int r = tid >> 2, ck = tid & 3;        // r: 0..63, ck: 0..3
    const ushort* src = vP + ((size_t)ch * Tp + t0 + r) * HD;
    *(bf16x8*)&tile[r][ck * 8]       = *(const bf16x8*)(src + ck * 8);
    *(bf16x8*)&tile[r][(ck + 4) * 8] = *(const bf16x8*)(src + (ck + 4) * 8);
    __syncthreads();
    // thread (r, ck) writes dim d=r, key chunks ck and ck+4
    ushort* dst = vT + ((size_t)ch * HD + r) * Tp + t0;
    short o1[8], o2[8];
#pragma unroll
    for (int j = 0; j < 8; ++j) {
        o1[j] = (short)tile[ck * 8 + j][r];
        o2[j] = (short)tile[(ck + 4) * 8 + j][r];
    }
    *(bf16x8*)(dst + ck * 8)       = *(bf16x8*)o1;
    *(bf16x8*)(dst + (ck + 4) * 8) = *(bf16x8*)o2;
}

// ---------------- MFMA flash attention v2 --------------------------------------
// grid (Tp/64, 64). 4 waves x 16 q-rows. 32-key steps, double-buffered staging,
// static-offset softmax (no running max), pre-transposed V, XOR-swizzled K.
__global__ __launch_bounds__(256) void attn_mfma(
    const ushort* __restrict__ qP, const ushort* __restrict__ kP,
    const ushort* __restrict__ vT,
    ushort* __restrict__ ohi, ushort* __restrict__ olo) {
    const int ch = blockIdx.y;
    const int c = ch >> 4, h = ch & 15;
    const int qbase = blockIdx.x * 64;
    const int tid = threadIdx.x, w = tid >> 6, lane = tid & 63;
    const int lrow = lane & 15, quad = lane >> 4;

    __shared__ ushort KT[2][32 * 64];    // [key][dim], XOR-swizzled 16B chunks
    __shared__ ushort VTs[2][64 * 32];   // [dim][key]
    __shared__ ushort PB[4][16][40];     // per-wave P   [qrow][key]

    const ushort* kg = kP + (size_t)ch * Tp * HD;
    const ushort* vg = vT + (size_t)ch * HD * Tp;

    // staging: K rows 64 ushorts, swizzle chunk = (lane%8)^((lane/8)%8)
    const ushort* kgl = kg + (size_t)(w * 8 + (lane >> 3)) * HD
                           + ((lane & 7) ^ ((lane >> 3) & 7)) * 8;
    const ushort* vgl = vg + (size_t)(w * 16 + (lane >> 2)) * Tp + (lane & 3) * 8;

    // Q A-frags (rows padded -> no guards)
    const int qr = qbase + w * 16 + lrow;
    const ushort* qgp = qP + ((size_t)ch * Tp + qr) * HD + quad * 8;
    bf16x8 qf0 = *(const bf16x8*)qgp;
    bf16x8 qf1 = *(const bf16x8*)(qgp + 32);

    f32x4 accO[4];
#pragma unroll
    for (int dt = 0; dt < 4; ++dt) accO[dt] = (f32x4){0.f, 0.f, 0.f, 0.f};
    float lacc[4] = {0.f, 0.f, 0.f, 0.f};

    // preload buffer 0
    gload_lds16(kgl, &KT[0][w * 512]);
    gload_lds16(vgl, &VTs[0][w * 512]);

    const int NSTEP = Tp / 32;                      // 40
    for (int s = 0; s < NSTEP; ++s) {
        const int b = s & 1;
        __syncthreads();                            // drains staging of buf b
        if (s + 1 < NSTEP) {                        // prefetch next into alt buf
            int kb = (s + 1) * 32;
            gload_lds16(kgl + (size_t)kb * HD, &KT[1 - b][w * 512]);
            gload_lds16(vgl + kb, &VTs[1 - b][w * 512]);
        }

        // ---- QK^T (plain bf16): 2 key-tiles x 2 dim-halves ----
        const int sw = lrow & 7;
        const ushort* r0 = &KT[b][lrow * 64];
        const ushort* r1 = &KT[b][(16 + lrow) * 64];
        bf16x8 k00 = *(const bf16x8*)(r0 + (quad ^ sw) * 8);
        bf16x8 k01 = *(const bf16x8*)(r0 + ((4 + quad) ^ sw) * 8);
        bf16x8 k10 = *(const bf16x8*)(r1 + (quad ^ sw) * 8);
        bf16x8 k11 = *(const bf16x8*)(r1 + ((4 + quad) ^ sw) * 8);
        f32x4 s0 = (f32x4){0.f, 0.f, 0.f, 0.f}, s1 = s0;
        s0 = __builtin_amdgcn_mfma_f32_16x16x32_bf16(qf0, k00, s0, 0, 0, 0);
        s0 = __builtin_amdgcn_mfma_f32_16x16x32_bf16(qf1, k01, s0, 0, 0, 0);
        s1 = __builtin_amdgcn_mfma_f32_16x16x32_bf16(qf0, k10, s1, 0, 0, 0);
        s1 = __builtin_amdgcn_mfma_f32_16x16x32_bf16(qf1, k11, s1, 0, 0, 0);

        // ---- static-offset softmax: p = exp(s - 8); no max, no rescale ----
#pragma unroll
        for (int r = 0; r < 4; ++r) {
            float p0 = __expf(s0[r] - OFFS);
            float p1 = __expf(s1[r] - OFFS);
            lacc[r] += p0 + p1;
            int row = quad * 4 + r;
            PB[w][row][lrow]      = f2bf(p0);
            PB[w][row][16 + lrow] = f2bf(p1);
        }

        // ---- P·V ----
        bf16x8 pf = *(const bf16x8*)&PB[w][lrow][quad * 8];
#pragma unroll
        for (int dt = 0; dt < 4; ++dt) {
            bf16x8 vf = *(const bf16x8*)&VTs[b][(dt * 16 + lrow) * 32 + quad * 8];
            accO[dt] = __builtin_amdgcn_mfma_f32_16x16x32_bf16(pf, vf, accO[dt], 0, 0, 0);
        }
    }

    // ---- epilogue: reduce l over the 16 lrow lanes; pad-key correction ----
    float il[4];
#pragma unroll
    for (int r = 0; r < 4; ++r) {
        float l = lacc[r];
        l += __shfl_xor(l, 1);
        l += __shfl_xor(l, 2);
        l += __shfl_xor(l, 4);
        l += __shfl_xor(l, 8);
        l -= (float)(Tp - Tt) * __expf(-OFFS);   // zero-K pad keys: p=e^-8, V=0
        il[r] = 1.f / l;
    }
#pragma unroll
    for (int dt = 0; dt < 4; ++dt)
#pragma unroll
        for (int r = 0; r < 4; ++r) {
            int qrow = qbase + w * 16 + quad * 4 + r;
            if (qrow < Tt) {
                float val = accO[dt][r] * il[r];
                size_t o = (size_t)(c * Tt + qrow) * Dm + h * HD + dt * 16 + lrow;
                ushort hv = f2bf(val);
                ohi[o] = hv;
                olo[o] = f2bf(val - bf2f(hv));
            }
        }
}

// ---------------- scatter/average back to sequence -> split planes -------------
__global__ __launch_bounds__(256) void scatter_emb(
    const float* __restrict__ proj,
    ushort* __restrict__ ehi, ushort* __restrict__ elo) {
    int idx = blockIdx.x * 256 + threadIdx.x;
    int row = idx >> 8, c4 = (idx & 255) * 4;
    float4 o;
    if (row < SEQ_TXT) {
        int c = row / TXT, t = row - c * TXT;
        o = *(const float4*)(proj + (size_t)(c * Tt + t) * Dm + c4);
    } else {
        int p = row - SEQ_TXT;
        float sx = 0.f, sy = 0.f, sz = 0.f, sw = 0.f; int cnt = 0;
#pragma unroll
        for (int c = 0; c < CHUNKS; ++c) {
            int off = p - c * STRIDE_V;
            if (off >= 0 && off < CHUNK_VID) {
                float4 x = *(const float4*)(proj + (size_t)(c * Tt + TXT + off) * Dm + c4);
                sx += x.x; sy += x.y; sz += x.z; sw += x.w; ++cnt;
            }
        }
        float inv = 1.f / (float)cnt;
        o = make_float4(sx * inv, sy * inv, sz * inv, sw * inv);
    }
    float v[4] = {o.x, o.y, o.z, o.w};
    ushort4 h, l;
    h.x = f2bf(v[0]); l.x = f2bf(v[0] - bf2f(h.x));
    h.y = f2bf(v[1]); l.y = f2bf(v[1] - bf2f(h.y));
    h.z = f2bf(v[2]); l.z = f2bf(v[2] - bf2f(h.z));
    h.w = f2bf(v[3]); l.w = f2bf(v[3] - bf2f(h.w));
    *(ushort4*)(ehi + (size_t)row * Dm + c4) = h;
    *(ushort4*)(elo + (size_t)row * Dm + c4) = l;
}

// ---------------- SSM scan (3-pass segmented) ----------------------------------
__global__ __launch_bounds__(256) void scan_carry(
    const float* __restrict__ u, const float* __restrict__ gate,
    float* __restrict__ carry, int perm) {
    int ch = blockIdx.x * 256 + threadIdx.x;
    int seg = blockIdx.y;
    float g = 1.f / (1.f + expf(-gate[ch]));
    int t0 = seg * SEGL, t1 = min(SEQm, t0 + SEGL);
    float hv = 0.f;
    for (int t = t0; t < t1; ++t) {
        int rt = perm ? rev_map(t) : t;
        hv = fmaf(g, hv, u[(size_t)rt * Dm + ch]);
    }
    carry[(size_t)seg * Dm + ch] = hv;
}

__global__ __launch_bounds__(256) void scan_combine(
    const float* __restrict__ carry, const float* __restrict__ gate,
    float* __restrict__ inc) {
    int ch = blockIdx.x * 256 + threadIdx.x;
    float g = 1.f / (1.f + expf(-gate[ch]));
    float gl = powf(g, (float)SEGL);
    float S = 0.f;
    for (int s = 0; s < NSEG; ++s) {
        inc[(size_t)s * Dm + ch] = S;
        int len = min(SEGL, SEQm - s * SEGL);
        float A = (len == SEGL) ? gl : powf(g, (float)len);
        S = fmaf(A, S, carry[(size_t)s * Dm + ch]);
    }
}

__global__ __launch_bounds__(256) void scan_final(
    const float* __restrict__ u, const float* __restrict__ gate,
    const float* __restrict__ inc,
    ushort* __restrict__ hhi, ushort* __restrict__ hlo, int perm) {
    int ch = blockIdx.x * 256 + threadIdx.x;
    int seg = blockIdx.y;
    float g = 1.f / (1.f + expf(-gate[ch]));
    int t0 = seg * SEGL, t1 = min(SEQm, t0 + SEGL);
    float hv = inc[(size_t)seg * Dm + ch];
    for (int t = t0; t < t1; ++t) {
        int rt = perm ? rev_map(t) : t;
        hv = fmaf(g, hv, u[(size_t)rt * Dm + ch]);
        ushort h = f2bf(hv);
        hhi[(size_t)rt * Dm + ch] = h;
        hlo[(size_t)rt * Dm + ch] = f2bf(hv - bf2f(h));
    }
}

// ---------------- elementwise combines -----------------------------------------
__global__ __launch_bounds__(256) void combine1(
    const ushort* __restrict__ ehi, const ushort* __restrict__ elo,
    const float* __restrict__ y,
    const float* __restrict__ fg_t, const float* __restrict__ fg_v,
    float* __restrict__ emb2, ushort* __restrict__ e2hi, ushort* __restrict__ e2lo) {
    int idx = blockIdx.x * 256 + threadIdx.x;
    int row = idx >> 8, c4 = (idx & 255) * 4;
    const float* fg = (row < SEQ_TXT) ? fg_t : fg_v;
    ushort4 eh = *(const ushort4*)(ehi + (size_t)row * Dm + c4);
    ushort4 el = *(const ushort4*)(elo + (size_t)row * Dm + c4);
    float4 yy = *(const float4*)(y + (size_t)row * Dm + c4);
    float v[4];
    v[0] = (bf2f(eh.x) + bf2f(el.x)) + tanhf(fg[c4 + 0]) * yy.x;
    v[1] = (bf2f(eh.y) + bf2f(el.y)) + tanhf(fg[c4 + 1]) * yy.y;
    v[2] = (bf2f(eh.z) + bf2f(el.z)) + tanhf(fg[c4 + 2]) * yy.z;
    v[3] = (bf2f(eh.w) + bf2f(el.w)) + tanhf(fg[c4 + 3]) * yy.w;
    *(float4*)(emb2 + (size_t)row * Dm + c4) = make_float4(v[0], v[1], v[2], v[3]);
    ushort4 h, l;
    h.x = f2bf(v[0]); l.x = f2bf(v[0] - bf2f(h.x));
    h.y = f2bf(v[1]); l.y = f2bf(v[1] - bf2f(h.y));
    h.z = f2bf(v[2]); l.z = f2bf(v[2] - bf2f(h.z));
    h.w = f2bf(v[3]); l.w = f2bf(v[3] - bf2f(h.w));
    *(ushort4*)(e2hi + (size_t)row * Dm + c4) = h;
    *(ushort4*)(e2lo + (size_t)row * Dm + c4) = l;
}

__global__ __launch_bounds__(256) void final_combine(
    const float* __restrict__ emb2, const float* __restrict__ y2,
    const float* __restrict__ bg_t, const float* __restrict__ bg_v,
    float* __restrict__ outp) {
    int idx = blockIdx.x * 256 + threadIdx.x;
    int row = idx >> 8, c4 = (idx & 255) * 4;
    const float* bg = (row < SEQ_TXT) ? bg_t : bg_v;
    int drow = (row >= SEQ_TXT) ? (row - SEQ_TXT) : (VID_LEN + row);
    float4 e = *(const float4*)(emb2 + (size_t)row * Dm + c4);
    float4 yy = *(const float4*)(y2 + (size_t)row * Dm + c4);
    float4 o = make_float4(e.x + tanhf(bg[c4 + 0]) * yy.x,
                           e.y + tanhf(bg[c4 + 1]) * yy.y,
                           e.z + tanhf(bg[c4 + 2]) * yy.z,
                           e.w + tanhf(bg[c4 + 3]) * yy.w);
    *(float4*)(outp + (size_t)drow * Dm + c4) = o;
}

// ---------------- host-side orchestration --------------------------------------
extern "C" void kernel_launch(void* const* d_in, const int* in_sizes, int n_in,
                              void* d_out, int out_size, void* d_ws, size_t ws_size,
                              hipStream_t stream) {
    const float* vid_emb = (const float*)d_in[0];
    const float* text_emb= (const float*)d_in[1];
    const float* Wq = (const float*)d_in[2];  const float* bq = (const float*)d_in[3];
    const float* Wk = (const float*)d_in[4];  const float* bk = (const float*)d_in[5];
    const float* Wv = (const float*)d_in[6];  const float* bv = (const float*)d_in[7];
    const float* Wo = (const float*)d_in[8];  const float* bo = (const float*)d_in[9];
    const float* qn_w = (const float*)d_in[10]; const float* qn_b = (const float*)d_in[11];
    const float* kn_w = (const float*)d_in[12]; const float* kn_b = (const float*)d_in[13];
    const float* Win  = (const float*)d_in[14]; const float* Wout = (const float*)d_in[15];
    const float* gate = (const float*)d_in[16];
    const float* fg_t = (const float*)d_in[17]; const float* fg_v = (const float*)d_in[18];
    const float* bg_t = (const float*)d_in[19]; const float* bg_v = (const float*)d_in[20];

    // ---- workspace layout (bytes). Sizes:
    //  qkvpre 61,440,000 | cur/aout plane 10,240,000 | q/k/v/vT plane 10,485,760
    //  proj 20,480,000 | emb/hbuf/e2 plane 8,667,136 | u/ybuf/emb2 17,334,272
    // Lifetime schedule (steps):
    //  3:QKV(cur->qkvpre) 4:lnrope(qkvpre->qkv) 5:transp(vP->vT)
    //  6:attn(q,k,vT->aout) 7:Wo(aout->proj) 8:scatter(proj->emb)
    //  9:Win(emb->u) 10:scan(u->hbuf) 11:Wout(hbuf->ybuf)
    //  12:comb1(emb,ybuf->emb2,e2) 13:Win(e2->u) 14:scan(u->hbuf)
    //  15:Wout(hbuf->ybuf) 16:final(emb2,ybuf->out)
    char* W8 = (char*)d_ws;
    if (ws_size < 137682944u) return;
    ushort* WqkvH = (ushort*)(W8 + 0);            // live all
    ushort* WqkvL = (ushort*)(W8 + 6291456);
    ushort* WoH   = (ushort*)(W8 + 12582912);
    ushort* WoL   = (ushort*)(W8 + 14680064);
    ushort* WinH  = (ushort*)(W8 + 16777216);
    ushort* WinL  = (ushort*)(W8 + 18874368);
    ushort* WoutH = (ushort*)(W8 + 20971520);
    ushort* WoutL = (ushort*)(W8 + 23068672);
    float*  b3    = (float*) (W8 + 25165824);
    float*  qkvpre= (float*) (W8 + 25178112);     // ends  86,618,112 (live 3-4)
    ushort* curH  = (ushort*)(W8 + 86618112);     // ends  96,858,112 (live 2-3)
    ushort* curL  = (ushort*)(W8 + 96858112);     // ends 107,098,112
    ushort* qPl   = (ushort*)(W8 + 86618112);     // ends  97,103,872 (live 4-6, over dead cur)
    ushort* kPl   = (ushort*)(W8 + 97103872);     // ends 107,589,632
    ushort* vPl   = (ushort*)(W8 + 107589632);    // ends 118,075,392 (live 4-5)
    ushort* vTl   = (ushort*)(W8 + 118075392);    // ends 128,561,152 (live 5-6)
    ushort* aoutH = (ushort*)(W8 + 25178112);     // ends  35,418,112 (live 6-7, over dead qkvpre)
    ushort* aoutL = (ushort*)(W8 + 35418112);     // ends  45,658,112
    float*  proj  = (float*) (W8 + 45658112);     // ends  66,138,112 (live 7-8)
    ushort* embH  = (ushort*)(W8 + 66138112);     // ends  74,805,248 (live 8-12)
    ushort* embL  = (ushort*)(W8 + 74805248);     // ends  83,472,384
    float*  u     = (float*) (W8 + 86618112);     // ends 103,952,384 (live 9-10,13-14; over dead q/k)
    ushort* hbufH = (ushort*)(W8 + 103952384);    // ends 112,619,520 (live 10-11,14-15)
    ushort* hbufL = (ushort*)(W8 + 112619520);    // ends 121,286,656
    float*  ybuf  = (float*) (W8 + 25178112);     // ends  42,512,384 (live 11-12,15-16; over dead aout)
    float*  emb2  = (float*) (W8 + 45658112);     // ends  62,992,384 (live 12-16; over dead proj)
    ushort* e2H   = (ushort*)(W8 + 103952384);    // ends 112,619,520 (live 12-13; over dead hbuf)
    ushort* e2L   = (ushort*)(W8 + 112619520);    // ends 121,286,656
    float*  carry = (float*) (W8 + 137404416);
    float*  incb  = (float*) (W8 + 137543680);    // need = 137,682,944
    float*  outp  = (float*)d_out;

    // ---- weight conversion (transpose + split) ----
    dim3 gw(32, 32);
    conv_w<<<gw, 256, 0, stream>>>(Wq, WqkvH, WqkvL);
    conv_w<<<gw, 256, 0, stream>>>(Wk, WqkvH + 1024 * 1024, WqkvL + 1024 * 1024);
    conv_w<<<gw, 256, 0, stream>>>(Wv, WqkvH + 2 * 1024 * 1024, WqkvL + 2 * 1024 * 1024);
    conv_w<<<gw, 256, 0, stream>>>(Wo, WoH, WoL);
    conv_w<<<gw, 256, 0, stream>>>(Win, WinH, WinL);
    conv_w<<<gw, 256, 0, stream>>>(Wout, WoutH, WoutL);
    conv_bias3<<<12, 256, 0, stream>>>(bq, bk, bv, b3);

    build_cur<<<M_QKV, 256, 0, stream>>>(vid_emb, text_emb, curH, curL);

    // fused QKV GEMM: [5000][3072]
    gemm_bf16s<<<dim3(24, 40), 256, 0, stream>>>(curH, curL, WqkvH, WqkvL, b3,
                                                 qkvpre, M_QKV, 3072);

    lnrope<<<(CHUNKS * Hh * Tp) / 4, 256, 0, stream>>>(qkvpre, qn_w, qn_b, kn_w, kn_b,
                                                       qPl, kPl, vPl);
    transpose_v<<<dim3(Tp / 64, 64), 256, 0, stream>>>(vPl, vTl);

    attn_mfma<<<dim3(Tp / 64, 64), 256, 0, stream>>>(qPl, kPl, vTl, aoutH, aoutL);

    gemm_bf16s<<<dim3(8, 40), 256, 0, stream>>>(aoutH, aoutL, WoH, WoL, bo,
                                                proj, M_QKV, 1024);

    scatter_emb<<<SEQm, 256, 0, stream>>>(proj, embH, embL);

    dim3 gsq(8, 34);
    dim3 gscan(Dm / 256, NSEG);

    // SSM forward
    gemm_bf16s<<<gsq, 256, 0, stream>>>(embH, embL, WinH, WinL, nullptr, u, SEQm, 1024);
    scan_carry<<<gscan, 256, 0, stream>>>(u, gate, carry, 0);
    scan_combine<<<Dm / 256, 256, 0, stream>>>(carry, gate, incb);
    scan_final<<<gscan, 256, 0, stream>>>(u, gate, incb, hbufH, hbufL, 0);
    gemm_bf16s<<<gsq, 256, 0, stream>>>(hbufH, hbufL, WoutH, WoutL, nullptr, ybuf, SEQm, 1024);
    combine1<<<SEQm, 256, 0, stream>>>(embH, embL, ybuf, fg_t, fg_v, emb2, e2H, e2L);

    // SSM backward (permuted scan; GEMMs commute with row permutation)
    gemm_bf16s<<<gsq, 256, 0, stream>>>(e2H, e2L, WinH, WinL, nullptr, u, SEQm, 1024);
    scan_carry<<<gscan, 256, 0, stream>>>(u, gate, carry, 1);
    scan_combine<<<Dm / 256, 256, 0, stream>>>(carry, gate, incb);
    scan_final<<<gscan, 256, 0, stream>>>(u, gate, incb, hbufH, hbufL, 1);
    gemm_bf16s<<<gsq, 256, 0, stream>>>(hbufH, hbufL, WoutH, WoutL, nullptr, ybuf, SEQm, 1024);

    final_combine<<<SEQm, 256, 0, stream>>>(emb2, ybuf, bg_t, bg_v, outp);
}

// Round 6
// 774.565 us; speedup vs baseline: 3.1800x; 1.0662x over previous
//
#include <hip/hip_runtime.h>
#include <cstdint>

// ---------------- problem constants ----------------
constexpr int Dm       = 1024;
constexpr int Hh       = 16;
constexpr int HD       = 64;
constexpr int CHUNKS   = 4;
constexpr int TXT      = 226;
constexpr int SEQ_TXT  = 904;        // CHUNKS*TXT
constexpr int VID_LEN  = 3328;       // FRAMES*TPF
constexpr int CHUNK_VID= 1024;       // (PREFIX+ATTN)*TPF
constexpr int Tt       = 1250;       // TXT + CHUNK_VID
constexpr int Tp       = 1280;       // padded (multiple of 64), rows >= Tt zeroed
constexpr int M_QKV    = 5000;       // CHUNKS*Tt
constexpr int SEQm     = 4232;       // SEQ_TXT + VID_LEN
constexpr int STRIDE_V = 768;        // ATTN*TPF
constexpr float EPSc   = 1e-6f;
constexpr float SCALEc = 0.125f;     // 1/sqrt(64)
constexpr float THETAc = 10000.f;
constexpr float OFFS   = 8.0f;       // |score| <= 8 by Cauchy-Schwarz (LN'd q,k)

constexpr int SEGL = 128;
constexpr int NSEG = (SEQm + SEGL - 1) / SEGL;   // 34

typedef __attribute__((ext_vector_type(8))) short bf16x8;
typedef __attribute__((ext_vector_type(4))) float f32x4;

__device__ __forceinline__ ushort f2bf(float x) {
    uint32_t u = __float_as_uint(x);
    u += 0x7FFFu + ((u >> 16) & 1u);
    return (ushort)(u >> 16);
}
__device__ __forceinline__ float bf2f(ushort b) {
    return __uint_as_float(((uint32_t)b) << 16);
}

// async global->LDS, 16B/lane. LDS dest = wave-uniform base + lane*16.
__device__ __forceinline__ void gload_lds16(const ushort* g, ushort* l) {
    __builtin_amdgcn_global_load_lds(
        (const __attribute__((address_space(1))) unsigned int*)g,
        (__attribute__((address_space(3))) unsigned int*)l, 16, 0, 0);
}

// reversal mapping (involution): text chunks flipped, video flipped
__device__ __forceinline__ int rev_map(int i) {
    if (i < SEQ_TXT) {
        int c = i / TXT, o = i - c * TXT;
        return (CHUNKS - 1 - c) * TXT + o;
    }
    int j = i - SEQ_TXT;
    return SEQ_TXT + (VID_LEN - 1 - j);
}

// ---------------- fused weight transpose + bf16 split (6 weights, 1 launch) ----
// T[n][k] = W[k][n]; z selects which weight.
__global__ __launch_bounds__(256) void conv_w_all(
    const float* __restrict__ Wq, const float* __restrict__ Wk,
    const float* __restrict__ Wv, const float* __restrict__ Wo,
    const float* __restrict__ Win, const float* __restrict__ Wout,
    ushort* __restrict__ WqkvH, ushort* __restrict__ WqkvL,
    ushort* __restrict__ WoH, ushort* __restrict__ WoL,
    ushort* __restrict__ WinH, ushort* __restrict__ WinL,
    ushort* __restrict__ WoutH, ushort* __restrict__ WoutL) {
    const float* W; ushort* Thi; ushort* Tlo;
    switch (blockIdx.z) {
        case 0: W = Wq;  Thi = WqkvH;               Tlo = WqkvL;               break;
        case 1: W = Wk;  Thi = WqkvH + 1024*1024;   Tlo = WqkvL + 1024*1024;   break;
        case 2: W = Wv;  Thi = WqkvH + 2*1024*1024; Tlo = WqkvL + 2*1024*1024; break;
        case 3: W = Wo;  Thi = WoH;   Tlo = WoL;   break;
        case 4: W = Win; Thi = WinH;  Tlo = WinL;  break;
        default:W = Wout;Thi = WoutH; Tlo = WoutL; break;
    }
    __shared__ float tile[32][33];
    int k0 = blockIdx.y * 32, n0 = blockIdx.x * 32;
    int j = threadIdx.x & 31, i0 = threadIdx.x >> 5;
#pragma unroll
    for (int i = i0; i < 32; i += 8)
        tile[i][j] = W[(size_t)(k0 + i) * 1024 + n0 + j];
    __syncthreads();
#pragma unroll
    for (int i = i0; i < 32; i += 8) {
        float v = tile[j][i];                    // W[k0+j][n0+i]
        ushort h = f2bf(v);
        size_t o = (size_t)(n0 + i) * 1024 + k0 + j;
        Thi[o] = h;
        Tlo[o] = f2bf(v - bf2f(h));
    }
}

// ---------------- assemble cur as split-bf16 planes [5000][1024] ---------------
__global__ __launch_bounds__(256) void build_cur(
    const float* __restrict__ vid, const float* __restrict__ txt,
    ushort* __restrict__ chi, ushort* __restrict__ clo) {
    int idx = blockIdx.x * 256 + threadIdx.x;
    int row = idx >> 8, c4 = (idx & 255) * 4;
    int c = row / Tt, t = row - c * Tt;
    float4 x;
    if (t < TXT)
        x = *(const float4*)(txt + (size_t)(c * TXT + t) * Dm + c4);
    else
        x = *(const float4*)(vid + (size_t)(c * STRIDE_V + (t - TXT)) * Dm + c4);
    float v[4] = {x.x, x.y, x.z, x.w};
    ushort4 h, l;
    h.x = f2bf(v[0]); l.x = f2bf(v[0] - bf2f(h.x));
    h.y = f2bf(v[1]); l.y = f2bf(v[1] - bf2f(h.y));
    h.z = f2bf(v[2]); l.z = f2bf(v[2] - bf2f(h.z));
    h.w = f2bf(v[3]); l.w = f2bf(v[3] - bf2f(h.w));
    *(ushort4*)(chi + (size_t)row * Dm + c4) = h;
    *(ushort4*)(clo + (size_t)row * Dm + c4) = l;
}

// ---------------- MFMA GEMM, split-bf16 3-product, 128x128 tile ----------------
// Conflict-free LDS: hi/lo interleaved into 128B rows, 16B chunks XOR-swizzled
// by (row&7); swizzle applied to the GLOBAL source so global_load_lds dest stays
// lane-contiguous. Epilogue fused per MODE:
//  0: fp32 C + bias f1            (Wo -> proj)
//  1: bf16 C + qkv bias select    (QKV -> qkvb)
//  2: fp32 C no bias              (Win -> u)
//  3: combine1: emb2/e2 from embH/L(r1,r2), gates f1/f2   (fwd Wout)
//  4: final_combine: out[drow] = emb2(f3) + tanh(bg)*acc  (bwd Wout)
template<int MODE>
__global__ __launch_bounds__(256) void gemm_sk(
    const ushort* __restrict__ Ahi, const ushort* __restrict__ Alo,
    const ushort* __restrict__ Bhi, const ushort* __restrict__ Blo,
    const float* __restrict__ f1, const float* __restrict__ f2,
    const float* __restrict__ f3,
    const ushort* __restrict__ r1, const ushort* __restrict__ r2,
    float* __restrict__ Cf, ushort* __restrict__ u1, ushort* __restrict__ u2,
    int M, int N) {
    __shared__ ushort AHL[128 * 64];   // [m][8 chunks x 8] hi/lo interleaved
    __shared__ ushort BHL[128 * 64];
    const int tid = threadIdx.x;
    const int w = tid >> 6, lane = tid & 63;
    const int lrow = lane & 15, quad = lane >> 4;
    const int mBase = blockIdx.y * 128, nBase = blockIdx.x * 128;

    // staging: waves 0,1 -> A halves; waves 2,3 -> B halves. 8 issues/wave,
    // each issue = 8 rows x 128B. lane covers (row lane>>3, slot lane&7);
    // logical chunk c = slot ^ (localrow&7); c<4 -> hi plane chunk c, else lo.
    const bool isB = (w >= 2);
    const int half = w & 1;
    const ushort* Phi = isB ? Bhi : Ahi;
    const ushort* Plo = isB ? Blo : Alo;
    ushort* lds = (isB ? BHL : AHL) + half * 4096;
    const int baseR = (isB ? nBase : mBase) + half * 64;
    const int maxr = (isB ? N : M) - 1;
    const int rl8 = lane >> 3;                   // row within 8-row group
    const int c = (lane & 7) ^ rl8;              // logical chunk for this lane
    const ushort* Psel = (c < 4) ? Phi : Plo;
    const ushort* gb[8];
#pragma unroll
    for (int u = 0; u < 8; ++u) {
        int rg = min(baseR + u * 8 + rl8, maxr);
        gb[u] = Psel + (size_t)rg * 1024 + (c & 3) * 8;
    }

    const int mo = (w >> 1) * 64, no = (w & 1) * 64;
    const int p = quad ^ (lrow & 7);             // hi slot; lo slot = p^4
    f32x4 acc[4][4];
#pragma unroll
    for (int i = 0; i < 4; ++i)
#pragma unroll
        for (int j = 0; j < 4; ++j) acc[i][j] = (f32x4){0.f, 0.f, 0.f, 0.f};

    for (int kk = 0; kk < 1024; kk += 32) {
        __syncthreads();
#pragma unroll
        for (int u = 0; u < 8; ++u) gload_lds16(gb[u] + kk, lds + u * 512);
        __syncthreads();

        bf16x8 ah[4], al[4], bh[4], bl[4];
#pragma unroll
        for (int i = 0; i < 4; ++i) {
            int m = mo + i * 16 + lrow;
            ah[i] = *(const bf16x8*)&AHL[m * 64 + p * 8];
            al[i] = *(const bf16x8*)&AHL[m * 64 + (p ^ 4) * 8];
        }
#pragma unroll
        for (int j = 0; j < 4; ++j) {
            int n = no + j * 16 + lrow;
            bh[j] = *(const bf16x8*)&BHL[n * 64 + p * 8];
            bl[j] = *(const bf16x8*)&BHL[n * 64 + (p ^ 4) * 8];
        }
#pragma unroll
        for (int i = 0; i < 4; ++i)
#pragma unroll
            for (int j = 0; j < 4; ++j) {
                f32x4 a = acc[i][j];
                a = __builtin_amdgcn_mfma_f32_16x16x32_bf16(ah[i], bh[j], a, 0, 0, 0);
                a = __builtin_amdgcn_mfma_f32_16x16x32_bf16(al[i], bh[j], a, 0, 0, 0);
                a = __builtin_amdgcn_mfma_f32_16x16x32_bf16(ah[i], bl[j], a, 0, 0, 0);
                acc[i][j] = a;
            }
    }

#pragma unroll
    for (int i = 0; i < 4; ++i)
#pragma unroll
        for (int j = 0; j < 4; ++j) {
            const int col = nBase + no + j * 16 + lrow;
            float bv = 0.f, tg_t = 0.f, tg_v = 0.f;
            if constexpr (MODE == 0) bv = f1[col];
            if constexpr (MODE == 1)
                bv = (col < 1024) ? f1[col]
                   : (col < 2048) ? f2[col - 1024] : f3[col - 2048];
            if constexpr (MODE == 3 || MODE == 4) {
                tg_t = tanhf(f1[col]);
                tg_v = tanhf(f2[col]);
            }
#pragma unroll
            for (int r = 0; r < 4; ++r) {
                const int row = mBase + mo + i * 16 + quad * 4 + r;
                if (row >= M) continue;
                const size_t idx = (size_t)row * N + col;
                const float a = acc[i][j][r];
                if constexpr (MODE == 0) {
                    Cf[idx] = a + bv;
                } else if constexpr (MODE == 1) {
                    u1[idx] = f2bf(a + bv);
                } else if constexpr (MODE == 2) {
                    Cf[idx] = a;
                } else if constexpr (MODE == 3) {
                    float e = bf2f(r1[idx]) + bf2f(r2[idx]);
                    float g = (row < SEQ_TXT) ? tg_t : tg_v;
                    float v = e + g * a;
                    Cf[idx] = v;
                    ushort hh = f2bf(v);
                    u1[idx] = hh;
                    u2[idx] = f2bf(v - bf2f(hh));
                } else {  // MODE 4
                    float e = f3[idx];
                    float g = (row < SEQ_TXT) ? tg_t : tg_v;
                    int drow = (row >= SEQ_TXT) ? (row - SEQ_TXT) : (VID_LEN + row);
                    Cf[(size_t)drow * N + col] = e + g * a;
                }
            }
        }
}

// ---------------- fused LayerNorm + RoPE3D + V-transpose -----------------------
// in: qkvb [5000][3072] bf16. out: qP/kP [ch][Tp][64] (q pre-scaled), vT [ch][64][Tp]
__global__ __launch_bounds__(256) void lnrope(
    const ushort* __restrict__ qkvb,
    const float* __restrict__ qn_w, const float* __restrict__ qn_b,
    const float* __restrict__ kn_w, const float* __restrict__ kn_b,
    ushort* __restrict__ qP, ushort* __restrict__ kP, ushort* __restrict__ vT) {
    __shared__ ushort vtile[64][72];
    const int ch = blockIdx.y, c = ch >> 4, h = ch & 15;
    const int t0 = blockIdx.x * 64;
    const int tid = threadIdx.x, w = tid >> 6, lane = tid & 63;

    auto wsum = [](float x) {
#pragma unroll
        for (int o = 32; o; o >>= 1) x += __shfl_xor(x, o);
        return x;
    };

#pragma unroll 1
    for (int it = 0; it < 16; ++it) {
        const int tl = w * 16 + it;
        const int t = t0 + tl;
        ushort qb = 0, kb = 0, vb = 0;
        if (t < Tt) {
            size_t src = (size_t)(c * Tt + t) * 3072 + h * HD + lane;
            float qv = bf2f(qkvb[src]);
            float kv = bf2f(qkvb[src + 1024]);
            float vv = bf2f(qkvb[src + 2048]);

            float qmu = wsum(qv) * (1.f / 64.f);
            float qd  = qv - qmu;
            float qvar = wsum(qd * qd) * (1.f / 64.f);
            float qn = qd * rsqrtf(qvar + EPSc) * qn_w[lane] + qn_b[lane];

            float kmu = wsum(kv) * (1.f / 64.f);
            float kd  = kv - kmu;
            float kvar = wsum(kd * kd) * (1.f / 64.f);
            float kn = kd * rsqrtf(kvar + EPSc) * kn_w[lane] + kn_b[lane];

            if (t >= TXT) {
                int pos = t - TXT;
                int f = pos >> 8, rem2 = pos & 255, hp = rem2 >> 4, wp = rem2 & 15;
                int dim, pp, dl;
                if (lane < 16)      { dim = 16; pp = f;  dl = lane; }
                else if (lane < 40) { dim = 24; pp = hp; dl = lane - 16; }
                else                { dim = 24; pp = wp; dl = lane - 40; }
                int halfd = dim >> 1;
                int i = (dl < halfd) ? dl : dl - halfd;
                float ang = (float)pp * powf(THETAc, -2.0f * (float)i / (float)dim);
                float cs = cosf(ang), sn = sinf(ang);
                int partner = (dl < halfd) ? (lane + halfd) : (lane - halfd);
                float qo = __shfl(qn, partner);
                float ko = __shfl(kn, partner);
                qn = (dl < halfd) ? (qn * cs - qo * sn) : (qo * sn + qn * cs);
                kn = (dl < halfd) ? (kn * cs - ko * sn) : (ko * sn + kn * cs);
            }
            qb = f2bf(qn * SCALEc);
            kb = f2bf(kn);
            vb = f2bf(vv);
        }
        size_t dst = ((size_t)ch * Tp + t) * HD + lane;
        qP[dst] = qb;
        kP[dst] = kb;
        vtile[tl][lane] = vb;
    }
    __syncthreads();
    // transpose V tile: thread (r=dim, ck) writes key chunks ck, ck+4
    const int r = tid >> 2, ck = tid & 3;
    ushort* dst = vT + ((size_t)ch * HD + r) * Tp + t0;
    short o1[8], o2[8];
#pragma unroll
    for (int j = 0; j < 8; ++j) {
        o1[j] = (short)vtile[ck * 8 + j][r];
        o2[j] = (short)vtile[(ck + 4) * 8 + j][r];
    }
    *(bf16x8*)(dst + ck * 8)       = *(bf16x8*)o1;
    *(bf16x8*)(dst + (ck + 4) * 8) = *(bf16x8*)o2;
}

// ---------------- MFMA flash attention (static-offset softmax) -----------------
__global__ __launch_bounds__(256) void attn_mfma(
    const ushort* __restrict__ qP, const ushort* __restrict__ kP,
    const ushort* __restrict__ vT,
    ushort* __restrict__ ohi, ushort* __restrict__ olo) {
    const int ch = blockIdx.y;
    const int c = ch >> 4, h = ch & 15;
    const int qbase = blockIdx.x * 64;
    const int tid = threadIdx.x, w = tid >> 6, lane = tid & 63;
    const int lrow = lane & 15, quad = lane >> 4;

    __shared__ ushort KT[2][32 * 64];    // [key][dim], XOR-swizzled 16B chunks
    __shared__ ushort VTs[2][64 * 32];   // [dim][key]
    __shared__ ushort PB[4][16][40];     // per-wave P   [qrow][key]

    const ushort* kg = kP + (size_t)ch * Tp * HD;
    const ushort* vg = vT + (size_t)ch * HD * Tp;

    const ushort* kgl = kg + (size_t)(w * 8 + (lane >> 3)) * HD
                           + ((lane & 7) ^ ((lane >> 3) & 7)) * 8;
    const ushort* vgl = vg + (size_t)(w * 16 + (lane >> 2)) * Tp + (lane & 3) * 8;

    const int qr = qbase + w * 16 + lrow;
    const ushort* qgp = qP + ((size_t)ch * Tp + qr) * HD + quad * 8;
    bf16x8 qf0 = *(const bf16x8*)qgp;
    bf16x8 qf1 = *(const bf16x8*)(qgp + 32);

    f32x4 accO[4];
#pragma unroll
    for (int dt = 0; dt < 4; ++dt) accO[dt] = (f32x4){0.f, 0.f, 0.f, 0.f};
    float lacc[4] = {0.f, 0.f, 0.f, 0.f};

    gload_lds16(kgl, &KT[0][w * 512]);
    gload_lds16(vgl, &VTs[0][w * 512]);

    const int NSTEP = Tp / 32;                      // 40
    for (int s = 0; s < NSTEP; ++s) {
        const int b = s & 1;
        __syncthreads();
        if (s + 1 < NSTEP) {
            int kb = (s + 1) * 32;
            gload_lds16(kgl + (size_t)kb * HD, &KT[1 - b][w * 512]);
            gload_lds16(vgl + kb, &VTs[1 - b][w * 512]);
        }

        const int sw = lrow & 7;
        const ushort* r0 = &KT[b][lrow * 64];
        const ushort* r1 = &KT[b][(16 + lrow) * 64];
        bf16x8 k00 = *(const bf16x8*)(r0 + (quad ^ sw) * 8);
        bf16x8 k01 = *(const bf16x8*)(r0 + ((4 + quad) ^ sw) * 8);
        bf16x8 k10 = *(const bf16x8*)(r1 + (quad ^ sw) * 8);
        bf16x8 k11 = *(const bf16x8*)(r1 + ((4 + quad) ^ sw) * 8);
        f32x4 s0 = (f32x4){0.f, 0.f, 0.f, 0.f}, s1 = s0;
        s0 = __builtin_amdgcn_mfma_f32_16x16x32_bf16(qf0, k00, s0, 0, 0, 0);
        s0 = __builtin_amdgcn_mfma_f32_16x16x32_bf16(qf1, k01, s0, 0, 0, 0);
        s1 = __builtin_amdgcn_mfma_f32_16x16x32_bf16(qf0, k10, s1, 0, 0, 0);
        s1 = __builtin_amdgcn_mfma_f32_16x16x32_bf16(qf1, k11, s1, 0, 0, 0);

#pragma unroll
        for (int r = 0; r < 4; ++r) {
            float p0 = __expf(s0[r] - OFFS);
            float p1 = __expf(s1[r] - OFFS);
            lacc[r] += p0 + p1;
            int row = quad * 4 + r;
            PB[w][row][lrow]      = f2bf(p0);
            PB[w][row][16 + lrow] = f2bf(p1);
        }

        bf16x8 pf = *(const bf16x8*)&PB[w][lrow][quad * 8];
#pragma unroll
        for (int dt = 0; dt < 4; ++dt) {
            bf16x8 vf = *(const bf16x8*)&VTs[b][(dt * 16 + lrow) * 32 + quad * 8];
            accO[dt] = __builtin_amdgcn_mfma_f32_16x16x32_bf16(pf, vf, accO[dt], 0, 0, 0);
        }
    }

    float il[4];
#pragma unroll
    for (int r = 0; r < 4; ++r) {
        float l = lacc[r];
        l += __shfl_xor(l, 1);
        l += __shfl_xor(l, 2);
        l += __shfl_xor(l, 4);
        l += __shfl_xor(l, 8);
        l -= (float)(Tp - Tt) * __expf(-OFFS);   // zero-K pad keys: p=e^-8, V=0
        il[r] = 1.f / l;
    }
#pragma unroll
    for (int dt = 0; dt < 4; ++dt)
#pragma unroll
        for (int r = 0; r < 4; ++r) {
            int qrow = qbase + w * 16 + quad * 4 + r;
            if (qrow < Tt) {
                float val = accO[dt][r] * il[r];
                size_t o = (size_t)(c * Tt + qrow) * Dm + h * HD + dt * 16 + lrow;
                ushort hv = f2bf(val);
                ohi[o] = hv;
                olo[o] = f2bf(val - bf2f(hv));
            }
        }
}

// ---------------- scatter/average back to sequence -> split planes -------------
__global__ __launch_bounds__(256) void scatter_emb(
    const float* __restrict__ proj,
    ushort* __restrict__ ehi, ushort* __restrict__ elo) {
    int idx = blockIdx.x * 256 + threadIdx.x;
    int row = idx >> 8, c4 = (idx & 255) * 4;
    float4 o;
    if (row < SEQ_TXT) {
        int c = row / TXT, t = row - c * TXT;
        o = *(const float4*)(proj + (size_t)(c * Tt + t) * Dm + c4);
    } else {
        int p = row - SEQ_TXT;
        float sx = 0.f, sy = 0.f, sz = 0.f, sw = 0.f; int cnt = 0;
#pragma unroll
        for (int c = 0; c < CHUNKS; ++c) {
            int off = p - c * STRIDE_V;
            if (off >= 0 && off < CHUNK_VID) {
                float4 x = *(const float4*)(proj + (size_t)(c * Tt + TXT + off) * Dm + c4);
                sx += x.x; sy += x.y; sz += x.z; sw += x.w; ++cnt;
            }
        }
        float inv = 1.f / (float)cnt;
        o = make_float4(sx * inv, sy * inv, sz * inv, sw * inv);
    }
    float v[4] = {o.x, o.y, o.z, o.w};
    ushort4 h, l;
    h.x = f2bf(v[0]); l.x = f2bf(v[0] - bf2f(h.x));
    h.y = f2bf(v[1]); l.y = f2bf(v[1] - bf2f(h.y));
    h.z = f2bf(v[2]); l.z = f2bf(v[2] - bf2f(h.z));
    h.w = f2bf(v[3]); l.w = f2bf(v[3] - bf2f(h.w));
    *(ushort4*)(ehi + (size_t)row * Dm + c4) = h;
    *(ushort4*)(elo + (size_t)row * Dm + c4) = l;
}

// ---------------- SSM scan (3-pass segmented) ----------------------------------
__global__ __launch_bounds__(256) void scan_carry(
    const float* __restrict__ u, const float* __restrict__ gate,
    float* __restrict__ carry, int perm) {
    int ch = blockIdx.x * 256 + threadIdx.x;
    int seg = blockIdx.y;
    float g = 1.f / (1.f + expf(-gate[ch]));
    int t0 = seg * SEGL, t1 = min(SEQm, t0 + SEGL);
    float hv = 0.f;
    for (int t = t0; t < t1; ++t) {
        int rt = perm ? rev_map(t) : t;
        hv = fmaf(g, hv, u[(size_t)rt * Dm + ch]);
    }
    carry[(size_t)seg * Dm + ch] = hv;
}

__global__ __launch_bounds__(256) void scan_combine(
    const float* __restrict__ carry, const float* __restrict__ gate,
    float* __restrict__ inc) {
    int ch = blockIdx.x * 256 + threadIdx.x;
    float g = 1.f / (1.f + expf(-gate[ch]));
    float gl = powf(g, (float)SEGL);
    float S = 0.f;
    for (int s = 0; s < NSEG; ++s) {
        inc[(size_t)s * Dm + ch] = S;
        int len = min(SEGL, SEQm - s * SEGL);
        float A = (len == SEGL) ? gl : powf(g, (float)len);
        S = fmaf(A, S, carry[(size_t)s * Dm + ch]);
    }
}

__global__ __launch_bounds__(256) void scan_final(
    const float* __restrict__ u, const float* __restrict__ gate,
    const float* __restrict__ inc,
    ushort* __restrict__ hhi, ushort* __restrict__ hlo, int perm) {
    int ch = blockIdx.x * 256 + threadIdx.x;
    int seg = blockIdx.y;
    float g = 1.f / (1.f + expf(-gate[ch]));
    int t0 = seg * SEGL, t1 = min(SEQm, t0 + SEGL);
    float hv = inc[(size_t)seg * Dm + ch];
    for (int t = t0; t < t1; ++t) {
        int rt = perm ? rev_map(t) : t;
        hv = fmaf(g, hv, u[(size_t)rt * Dm + ch]);
        ushort h = f2bf(hv);
        hhi[(size_t)rt * Dm + ch] = h;
        hlo[(size_t)rt * Dm + ch] = f2bf(hv - bf2f(h));
    }
}

// ---------------- host-side orchestration --------------------------------------
extern "C" void kernel_launch(void* const* d_in, const int* in_sizes, int n_in,
                              void* d_out, int out_size, void* d_ws, size_t ws_size,
                              hipStream_t stream) {
    const float* vid_emb = (const float*)d_in[0];
    const float* text_emb= (const float*)d_in[1];
    const float* Wq = (const float*)d_in[2];  const float* bq = (const float*)d_in[3];
    const float* Wk = (const float*)d_in[4];  const float* bk = (const float*)d_in[5];
    const float* Wv = (const float*)d_in[6];  const float* bv = (const float*)d_in[7];
    const float* Wo = (const float*)d_in[8];  const float* bo = (const float*)d_in[9];
    const float* qn_w = (const float*)d_in[10]; const float* qn_b = (const float*)d_in[11];
    const float* kn_w = (const float*)d_in[12]; const float* kn_b = (const float*)d_in[13];
    const float* Win  = (const float*)d_in[14]; const float* Wout = (const float*)d_in[15];
    const float* gate = (const float*)d_in[16];
    const float* fg_t = (const float*)d_in[17]; const float* fg_v = (const float*)d_in[18];
    const float* bg_t = (const float*)d_in[19]; const float* bg_v = (const float*)d_in[20];

    // ---- workspace layout (bytes); lifetimes:
    //  build(cur) -> QKV(cur->qkvb) -> lnrope(qkvb->q,k,vT) -> attn(->aout)
    //  -> Wo(aout->proj) -> scatter(proj->emb) -> Win(emb->u) -> scan(u->hbuf)
    //  -> WoutC1(hbuf,emb->emb2,e2) -> Win(e2->u) -> scan(u->hbuf)
    //  -> WoutFin(hbuf,emb2->out)
    char* W8 = (char*)d_ws;
    if (ws_size < 132284416u) return;
    ushort* WqkvH = (ushort*)(W8 + 0);            // weights: live all
    ushort* WqkvL = (ushort*)(W8 + 6291456);
    ushort* WoH   = (ushort*)(W8 + 12582912);
    ushort* WoL   = (ushort*)(W8 + 14680064);
    ushort* WinH  = (ushort*)(W8 + 16777216);
    ushort* WinL  = (ushort*)(W8 + 18874368);
    ushort* WoutH = (ushort*)(W8 + 20971520);
    ushort* WoutL = (ushort*)(W8 + 23068672);     // ends 25,165,824
    ushort* qkvb  = (ushort*)(W8 + 25165824);     // [5000][3072] ends 55,885,824
    ushort* curH  = (ushort*)(W8 + 55885824);     // ends 66,125,824
    ushort* curL  = (ushort*)(W8 + 66125824);     // ends 76,365,824
    ushort* qPl   = (ushort*)(W8 + 76365824);     // [64][1280][64] ends 86,851,584
    ushort* kPl   = (ushort*)(W8 + 86851584);     // ends 97,337,344
    ushort* vTl   = (ushort*)(W8 + 97337344);     // ends 107,823,104
    ushort* aoutH = (ushort*)(W8 + 25165824);     // over dead qkvb; ends 35,405,824
    ushort* aoutL = (ushort*)(W8 + 35405824);     // ends 45,645,824
    float*  proj  = (float*) (W8 + 55885824);     // over dead cur; ends 76,365,824
    ushort* embH  = (ushort*)(W8 + 25165824);     // over dead aout; ends 33,832,960
    ushort* embL  = (ushort*)(W8 + 33832960);     // ends 42,500,096
    float*  u     = (float*) (W8 + 55885824);     // over dead proj; ends 73,220,096
    ushort* hbufH = (ushort*)(W8 + 76365824);     // over dead qPl; ends 85,032,960
    ushort* hbufL = (ushort*)(W8 + 85032960);     // ends 93,700,096
    float*  emb2  = (float*) (W8 + 97337344);     // over dead vTl; ends 114,671,616
    ushort* e2H   = (ushort*)(W8 + 114671616);    // ends 123,338,752
    ushort* e2L   = (ushort*)(W8 + 123338752);    // ends 132,005,888
    float*  carry = (float*) (W8 + 132005888);    // ends 132,145,152
    float*  incb  = (float*) (W8 + 132145152);    // ends 132,284,416
    float*  outp  = (float*)d_out;

    conv_w_all<<<dim3(32, 32, 6), 256, 0, stream>>>(
        Wq, Wk, Wv, Wo, Win, Wout,
        WqkvH, WqkvL, WoH, WoL, WinH, WinL, WoutH, WoutL);

    build_cur<<<M_QKV, 256, 0, stream>>>(vid_emb, text_emb, curH, curL);

    // QKV GEMM -> bf16 [5000][3072], bias select in epilogue
    gemm_sk<1><<<dim3(24, 40), 256, 0, stream>>>(
        curH, curL, WqkvH, WqkvL, bq, bk, bv, nullptr, nullptr,
        nullptr, qkvb, nullptr, M_QKV, 3072);

    lnrope<<<dim3(Tp / 64, 64), 256, 0, stream>>>(qkvb, qn_w, qn_b, kn_w, kn_b,
                                                  qPl, kPl, vTl);

    attn_mfma<<<dim3(Tp / 64, 64), 256, 0, stream>>>(qPl, kPl, vTl, aoutH, aoutL);

    gemm_sk<0><<<dim3(8, 40), 256, 0, stream>>>(
        aoutH, aoutL, WoH, WoL, bo, nullptr, nullptr, nullptr, nullptr,
        proj, nullptr, nullptr, M_QKV, 1024);

    scatter_emb<<<SEQm, 256, 0, stream>>>(proj, embH, embL);

    dim3 gsq(8, 34);
    dim3 gscan(Dm / 256, NSEG);

    // SSM forward
    gemm_sk<2><<<gsq, 256, 0, stream>>>(
        embH, embL, WinH, WinL, nullptr, nullptr, nullptr, nullptr, nullptr,
        u, nullptr, nullptr, SEQm, 1024);
    scan_carry<<<gscan, 256, 0, stream>>>(u, gate, carry, 0);
    scan_combine<<<Dm / 256, 256, 0, stream>>>(carry, gate, incb);
    scan_final<<<gscan, 256, 0, stream>>>(u, gate, incb, hbufH, hbufL, 0);
    // Wout GEMM + combine1 epilogue -> emb2 fp32 + e2 planes
    gemm_sk<3><<<gsq, 256, 0, stream>>>(
        hbufH, hbufL, WoutH, WoutL, fg_t, fg_v, nullptr, embH, embL,
        emb2, e2H, e2L, SEQm, 1024);

    // SSM backward (permuted scan; GEMMs commute with row permutation)
    gemm_sk<2><<<gsq, 256, 0, stream>>>(
        e2H, e2L, WinH, WinL, nullptr, nullptr, nullptr, nullptr, nullptr,
        u, nullptr, nullptr, SEQm, 1024);
    scan_carry<<<gscan, 256, 0, stream>>>(u, gate, carry, 1);
    scan_combine<<<Dm / 256, 256, 0, stream>>>(carry, gate, incb);
    scan_final<<<gscan, 256, 0, stream>>>(u, gate, incb, hbufH, hbufL, 1);
    // Wout GEMM + final_combine epilogue -> outp (row-permuted)
    gemm_sk<4><<<gsq, 256, 0, stream>>>(
        hbufH, hbufL, WoutH, WoutL, bg_t, bg_v, emb2, nullptr, nullptr,
        outp, nullptr, nullptr, SEQm, 1024);
}